// Round 1
// baseline (3077.214 us; speedup 1.0000x reference)
//
#include <hip/hip_runtime.h>
#include <hip/hip_bf16.h>
#include <math.h>

#define BQ 8
#define NPER 2048
#define EPER 32768
#define NTOT (BQ * NPER)          // 16384
#define ETOT (BQ * EPER)          // 262144
#define HDIM 128
#define TWOH 256
#define LNUM 3
#define ESIZE 50                  // gaussian basis count
#define TILE_E 32
#define SP_STRIDE 260             // padded 2H stride (multiple of 4, breaks bank alias)
#define H1_STRIDE 132             // padded H stride
#define RBF_STRIDE 52

__device__ __forceinline__ float sspf(float x) {
    // softplus(x) - log(2), numerically stable
    float ax = fabsf(x);
    return fmaxf(x, 0.0f) + log1pf(expf(-ax)) - 0.6931471805599453f;
}

// Chunked K-staged GEMM accumulate: acc[4][4] += A_lds[eA+i][k] * W[k][tf*4+j]
// A_lds is an LDS tile with row stride astride; W is global [K][128].
__device__ __forceinline__ void gemm_phase(const float* A, int astride,
                                           const float* __restrict__ W, int K,
                                           float* wl, float acc[4][4],
                                           int tid, int eA, int tf)
{
    for (int kk = 0; kk < K; kk += 16) {
        int kc = K - kk; if (kc > 16) kc = 16;
        for (int i = tid; i < kc * HDIM; i += 256)
            wl[i] = W[(kk + (i >> 7)) * HDIM + (i & 127)];
        __syncthreads();
        #pragma unroll 16
        for (int k = 0; k < kc; ++k) {
            float4 b = *(const float4*)&wl[k * HDIM + tf * 4];
            #pragma unroll
            for (int i = 0; i < 4; ++i) {
                float a = A[(eA + i) * astride + kk + k];
                acc[i][0] = fmaf(a, b.x, acc[i][0]);
                acc[i][1] = fmaf(a, b.y, acc[i][1]);
                acc[i][2] = fmaf(a, b.z, acc[i][2]);
                acc[i][3] = fmaf(a, b.w, acc[i][3]);
            }
        }
        __syncthreads();
    }
}

__global__ __launch_bounds__(256) void init_nodes_kernel(
    const int* __restrict__ nodes, const float* __restrict__ emb,
    float* __restrict__ node_state)
{
    int i = blockIdx.x * 256 + threadIdx.x;   // NTOT*H total
    int n = i >> 7, f = i & 127;
    node_state[i] = emb[nodes[n] * HDIM + f];
}

__global__ __launch_bounds__(256) void edge_setup_kernel(
    const int* __restrict__ atom_edges, const float* __restrict__ aef,
    int* __restrict__ send, int* __restrict__ recv, float* __restrict__ cut)
{
    int g = blockIdx.x * 256 + threadIdx.x;
    if (g >= ETOT) return;
    int b = g >> 15;                            // EPER = 2^15
    send[g] = atom_edges[2 * g + 0] + b * NPER;
    recv[g] = atom_edges[2 * g + 1] + b * NPER;
    float dd = aef[g];
    cut[g] = 1.0f - 1.0f / (1.0f + expf(-5.0f * (dd - 3.5f)));
}

__global__ __launch_bounds__(256) void edge_mlp_kernel(
    const float* __restrict__ node_state,
    const int* __restrict__ send, const int* __restrict__ recv,
    const float* __restrict__ dfeat, const float* __restrict__ cut,
    const float* __restrict__ Wn1, const float* __restrict__ bn1,
    const float* __restrict__ Wn2, const float* __restrict__ bn2,
    const float* __restrict__ We1, const float* __restrict__ be1,
    const float* __restrict__ We2, const float* __restrict__ be2,
    float* __restrict__ msum)
{
    __shared__ float sp[TILE_E * SP_STRIDE];     // pair tile [32][2H]
    __shared__ float h1[TILE_E * H1_STRIDE];     // hidden tile [32][H] (reused for gate hidden)
    __shared__ float wl[16 * HDIM];              // weight chunk
    __shared__ float rbf[TILE_E * RBF_STRIDE];   // gaussian basis [32][50]
    __shared__ int   sl[TILE_E], rl[TILE_E];
    __shared__ float cutl[TILE_E];

    int tid = threadIdx.x;
    int e0g = blockIdx.x * TILE_E;

    if (tid < TILE_E) {
        sl[tid]   = send[e0g + tid];
        rl[tid]   = recv[e0g + tid];
        cutl[tid] = cut[e0g + tid];
    }
    __syncthreads();

    // gather sender||receiver states
    for (int i = tid; i < TILE_E * TWOH; i += 256) {
        int e = i >> 8, k = i & 255;
        int nidx = (k < HDIM) ? sl[e] : rl[e];
        sp[e * SP_STRIDE + k] = node_state[nidx * HDIM + (k & (HDIM - 1))];
    }
    // gaussian radial basis, sigma = 0.1: exp(-50*(d-mu)^2)
    for (int i = tid; i < TILE_E * ESIZE; i += 256) {
        int e = i / ESIZE, k = i - e * ESIZE;
        float dd = dfeat[e0g + e] - 0.1f * (float)k;
        rbf[e * RBF_STRIDE + k] = expf(-50.0f * dd * dd);
    }
    __syncthreads();

    int te = tid >> 5, tf = tid & 31;
    int eA = te * 4;

    // ---- phase 1: h1 = ssp(pair @ Wn1 + bn1)
    float acc[4][4];
    #pragma unroll
    for (int i = 0; i < 4; ++i)
        #pragma unroll
        for (int j = 0; j < 4; ++j) acc[i][j] = 0.0f;
    gemm_phase(sp, SP_STRIDE, Wn1, TWOH, wl, acc, tid, eA, tf);
    {
        float4 bb = *(const float4*)&bn1[tf * 4];
        #pragma unroll
        for (int i = 0; i < 4; ++i) {
            float4 v;
            v.x = sspf(acc[i][0] + bb.x);
            v.y = sspf(acc[i][1] + bb.y);
            v.z = sspf(acc[i][2] + bb.z);
            v.w = sspf(acc[i][3] + bb.w);
            *(float4*)&h1[(eA + i) * H1_STRIDE + tf * 4] = v;
        }
    }
    __syncthreads();

    // ---- phase 2: m_node = h1 @ Wn2 + bn2  (kept in registers)
    float mn[4][4];
    #pragma unroll
    for (int i = 0; i < 4; ++i)
        #pragma unroll
        for (int j = 0; j < 4; ++j) mn[i][j] = 0.0f;
    gemm_phase(h1, H1_STRIDE, Wn2, HDIM, wl, mn, tid, eA, tf);
    {
        float4 bb = *(const float4*)&bn2[tf * 4];
        #pragma unroll
        for (int i = 0; i < 4; ++i) {
            mn[i][0] += bb.x; mn[i][1] += bb.y; mn[i][2] += bb.z; mn[i][3] += bb.w;
        }
    }

    // ---- phase 3: gate hidden = ssp(rbf @ We1 + be1) -> overwrite h1
    #pragma unroll
    for (int i = 0; i < 4; ++i)
        #pragma unroll
        for (int j = 0; j < 4; ++j) acc[i][j] = 0.0f;
    gemm_phase(rbf, RBF_STRIDE, We1, ESIZE, wl, acc, tid, eA, tf);
    __syncthreads();  // everyone done reading h1 in phase 2 (already synced), safety for write
    {
        float4 bb = *(const float4*)&be1[tf * 4];
        #pragma unroll
        for (int i = 0; i < 4; ++i) {
            float4 v;
            v.x = sspf(acc[i][0] + bb.x);
            v.y = sspf(acc[i][1] + bb.y);
            v.z = sspf(acc[i][2] + bb.z);
            v.w = sspf(acc[i][3] + bb.w);
            *(float4*)&h1[(eA + i) * H1_STRIDE + tf * 4] = v;
        }
    }
    __syncthreads();

    // ---- phase 4: gates = (h1 @ We2 + be2) * cut
    float gt[4][4];
    #pragma unroll
    for (int i = 0; i < 4; ++i)
        #pragma unroll
        for (int j = 0; j < 4; ++j) gt[i][j] = 0.0f;
    gemm_phase(h1, H1_STRIDE, We2, HDIM, wl, gt, tid, eA, tf);

    // ---- combine + scatter-add
    {
        float4 bb = *(const float4*)&be2[tf * 4];
        #pragma unroll
        for (int i = 0; i < 4; ++i) {
            float cu = cutl[eA + i];
            int rnode = rl[eA + i];
            float m0 = mn[i][0] * ((gt[i][0] + bb.x) * cu);
            float m1 = mn[i][1] * ((gt[i][1] + bb.y) * cu);
            float m2 = mn[i][2] * ((gt[i][2] + bb.z) * cu);
            float m3 = mn[i][3] * ((gt[i][3] + bb.w) * cu);
            float* dst = &msum[(size_t)rnode * HDIM + tf * 4];
            atomicAdd(dst + 0, m0);
            atomicAdd(dst + 1, m1);
            atomicAdd(dst + 2, m2);
            atomicAdd(dst + 3, m3);
        }
    }
}

__global__ __launch_bounds__(256) void node_update_kernel(
    float* __restrict__ node_state, const float* __restrict__ msum,
    const float* __restrict__ Ws1, const float* __restrict__ bs1,
    const float* __restrict__ Ws2, const float* __restrict__ bs2,
    float* __restrict__ out_l)
{
    __shared__ float a_lds[32 * H1_STRIDE];
    __shared__ float h_lds[32 * H1_STRIDE];
    __shared__ float wl[16 * HDIM];

    int tid = threadIdx.x;
    int r0 = blockIdx.x * 32;

    for (int i = tid; i < 32 * HDIM; i += 256) {
        int r = i >> 7, f = i & 127;
        a_lds[r * H1_STRIDE + f] = msum[(size_t)(r0 + r) * HDIM + f];
    }
    __syncthreads();

    int te = tid >> 5, tf = tid & 31;
    int rA = te * 4;

    float acc[4][4];
    #pragma unroll
    for (int i = 0; i < 4; ++i)
        #pragma unroll
        for (int j = 0; j < 4; ++j) acc[i][j] = 0.0f;
    gemm_phase(a_lds, H1_STRIDE, Ws1, HDIM, wl, acc, tid, rA, tf);
    {
        float4 bb = *(const float4*)&bs1[tf * 4];
        #pragma unroll
        for (int i = 0; i < 4; ++i) {
            float4 v;
            v.x = sspf(acc[i][0] + bb.x);
            v.y = sspf(acc[i][1] + bb.y);
            v.z = sspf(acc[i][2] + bb.z);
            v.w = sspf(acc[i][3] + bb.w);
            *(float4*)&h_lds[(rA + i) * H1_STRIDE + tf * 4] = v;
        }
    }
    __syncthreads();

    float d2[4][4];
    #pragma unroll
    for (int i = 0; i < 4; ++i)
        #pragma unroll
        for (int j = 0; j < 4; ++j) d2[i][j] = 0.0f;
    gemm_phase(h_lds, H1_STRIDE, Ws2, HDIM, wl, d2, tid, rA, tf);

    {
        float4 bb = *(const float4*)&bs2[tf * 4];
        #pragma unroll
        for (int i = 0; i < 4; ++i) {
            size_t idx = (size_t)(r0 + rA + i) * HDIM + tf * 4;
            float4 ns = *(const float4*)&node_state[idx];
            ns.x += d2[i][0] + bb.x;
            ns.y += d2[i][1] + bb.y;
            ns.z += d2[i][2] + bb.z;
            ns.w += d2[i][3] + bb.w;
            *(float4*)&node_state[idx] = ns;
            *(float4*)&out_l[idx] = ns;
        }
    }
}

extern "C" void kernel_launch(void* const* d_in, const int* in_sizes, int n_in,
                              void* d_out, int out_size, void* d_ws, size_t ws_size,
                              hipStream_t stream)
{
    const int*   nodes      = (const int*)d_in[0];
    const int*   atom_edges = (const int*)d_in[1];
    const float* aef        = (const float*)d_in[2];
    // d_in[3] num_nodes, d_in[4] num_atom_edges: constant (full) — unused
    const float* emb = (const float*)d_in[5];
    const float* Wn1 = (const float*)d_in[6];
    const float* bn1 = (const float*)d_in[7];
    const float* Wn2 = (const float*)d_in[8];
    const float* bn2 = (const float*)d_in[9];
    const float* We1 = (const float*)d_in[10];
    const float* be1 = (const float*)d_in[11];
    const float* We2 = (const float*)d_in[12];
    const float* be2 = (const float*)d_in[13];
    const float* Ws1 = (const float*)d_in[14];
    const float* bs1 = (const float*)d_in[15];
    const float* Ws2 = (const float*)d_in[16];
    const float* bs2 = (const float*)d_in[17];
    float* out = (float*)d_out;

    char* ws = (char*)d_ws;
    float* node_state = (float*)(ws);                      // 8 MB
    float* msum       = (float*)(ws + (8u << 20));         // 8 MB
    int*   send       = (int*)  (ws + (16u << 20));        // 1 MB
    int*   recv       = (int*)  (ws + (17u << 20));        // 1 MB
    float* cut        = (float*)(ws + (18u << 20));        // 1 MB

    init_nodes_kernel<<<NTOT * HDIM / 256, 256, 0, stream>>>(nodes, emb, node_state);
    edge_setup_kernel<<<ETOT / 256, 256, 0, stream>>>(atom_edges, aef, send, recv, cut);

    for (int l = 0; l < LNUM; ++l) {
        hipMemsetAsync(msum, 0, (size_t)NTOT * HDIM * sizeof(float), stream);
        edge_mlp_kernel<<<ETOT / TILE_E, 256, 0, stream>>>(
            node_state, send, recv, aef, cut,
            Wn1 + (size_t)l * TWOH * HDIM, bn1 + (size_t)l * HDIM,
            Wn2 + (size_t)l * HDIM * HDIM, bn2 + (size_t)l * HDIM,
            We1 + (size_t)l * ESIZE * HDIM, be1 + (size_t)l * HDIM,
            We2 + (size_t)l * HDIM * HDIM, be2 + (size_t)l * HDIM,
            msum);
        node_update_kernel<<<NTOT / 32, 256, 0, stream>>>(
            node_state, msum,
            Ws1 + (size_t)l * HDIM * HDIM, bs1 + (size_t)l * HDIM,
            Ws2 + (size_t)l * HDIM * HDIM, bs2 + (size_t)l * HDIM,
            out + (size_t)l * NTOT * HDIM);
    }
}

// Round 2
// 1286.454 us; speedup vs baseline: 2.3920x; 2.3920x over previous
//
#include <hip/hip_runtime.h>
#include <hip/hip_bf16.h>
#include <math.h>

#define BQ 8
#define NPER 2048
#define EPER 32768
#define NTOT (BQ * NPER)          // 16384
#define ETOT (BQ * EPER)          // 262144
#define HDIM 128
#define LNUM 3

typedef __attribute__((ext_vector_type(8))) short short8;
typedef __attribute__((ext_vector_type(4))) float f32x4;

__device__ __forceinline__ short f2bf(float x) {
    union { float f; unsigned u; } v; v.f = x;
    unsigned r = v.u + 0x7fffu + ((v.u >> 16) & 1u);
    return (short)(r >> 16);
}
__device__ __forceinline__ float bf2f(unsigned hi16) {
    union { unsigned u; float f; } v; v.u = hi16 << 16; return v.f;
}
__device__ __forceinline__ unsigned pack2(float a, float b) {
    return (unsigned)(unsigned short)f2bf(a) | ((unsigned)(unsigned short)f2bf(b) << 16);
}
__device__ __forceinline__ float sspf(float x) {
    // softplus(x) - ln2 = ln2*(log2(1+2^(x/ln2)) - 1); activations bounded, no overflow risk
    return 0.6931471805599453f * (log2f(1.0f + exp2f(x * 1.4426950408889634f)) - 1.0f);
}

// ---------------- once-per-launch prep ----------------

// WT[l][n][p] = bf16(W[l][k(p)][n]), k-permutation optional (for packed bf16x2 layouts)
__global__ __launch_bounds__(256) void wprep_kernel(
    const float* __restrict__ W, unsigned short* __restrict__ WT,
    int K, int KP, int doperm)
{
    int idx = blockIdx.x * 256 + threadIdx.x;
    int total = LNUM * 128 * KP;
    if (idx >= total) return;
    int l = idx / (128 * KP);
    int rem = idx - l * (128 * KP);
    int n = rem / KP;
    int p = rem - n * KP;
    int k;
    if (doperm) {
        int half = p >> 7, pp = p & 127;
        k = (half << 7) | ((pp >> 5) << 5) | ((pp & 1) << 4) | ((pp & 31) >> 1);
    } else k = p;
    float v = (k < K) ? W[((size_t)l * K + k) * 128 + n] : 0.0f;
    WT[idx] = (unsigned short)f2bf(v);
}

__global__ __launch_bounds__(256) void init_nodes_kernel(
    const int* __restrict__ nodes, const float* __restrict__ emb,
    float* __restrict__ node_state, unsigned short* __restrict__ nsb)
{
    int idx = blockIdx.x * 256 + threadIdx.x;  // NTOT*128
    int n = idx >> 7, p = idx & 127;
    int j = ((p >> 5) << 5) | ((p & 1) << 4) | ((p & 31) >> 1);   // permuted feature
    float v = emb[(size_t)nodes[n] * 128 + j];
    nsb[idx] = (unsigned short)f2bf(v);
    node_state[(n << 7) + j] = v;
}

__global__ __launch_bounds__(256) void count_kernel(const int* __restrict__ ae, int* __restrict__ cnt)
{
    int g = blockIdx.x * 256 + threadIdx.x;
    int b = g >> 15;
    atomicAdd(&cnt[ae[2 * g + 1] + b * NPER], 1);
}

__global__ __launch_bounds__(256) void scan_kernel(
    const int* __restrict__ cnt, int* __restrict__ segs, int* __restrict__ cursor)
{
    __shared__ int part[256];
    int t = threadIdx.x;
    int base = t * 64;
    int s = 0;
    for (int i = 0; i < 64; ++i) s += cnt[base + i];
    part[t] = s;
    __syncthreads();
    for (int ofs = 1; ofs < 256; ofs <<= 1) {
        int v = part[t];
        int add = (t >= ofs) ? part[t - ofs] : 0;
        __syncthreads();
        part[t] = v + add;
        __syncthreads();
    }
    int run = part[t] - s;   // exclusive base for this chunk
    for (int i = 0; i < 64; ++i) {
        segs[base + i] = run;
        cursor[base + i] = run;
        run += cnt[base + i];
    }
    if (t == 255) segs[NTOT] = run;
}

__global__ __launch_bounds__(256) void scatter_kernel(
    const int* __restrict__ ae, const float* __restrict__ aef, int* __restrict__ cursor,
    int* __restrict__ ssend, int* __restrict__ srecv,
    float* __restrict__ sdv, float* __restrict__ scv)
{
    int g = blockIdx.x * 256 + threadIdx.x;
    int b = g >> 15;
    int sn = ae[2 * g] + b * NPER, rv = ae[2 * g + 1] + b * NPER;
    int pos = atomicAdd(&cursor[rv], 1);
    ssend[pos] = sn; srecv[pos] = rv;
    float dd = aef[g];
    sdv[pos] = dd;
    scv[pos] = 1.0f - 1.0f / (1.0f + expf(-5.0f * (dd - 3.5f)));
}

// ---------------- per-layer: edge messages (MFMA) ----------------

__global__ __launch_bounds__(256) void edge_mfma_kernel(
    const unsigned short* __restrict__ nsb,
    const int* __restrict__ ssend, const int* __restrict__ srecv,
    const float* __restrict__ sd, const float* __restrict__ scut,
    const unsigned short* __restrict__ WT1, const float* __restrict__ bn1,
    const unsigned short* __restrict__ WT2, const float* __restrict__ bn2,
    const unsigned short* __restrict__ WTe1, const float* __restrict__ be1,
    const unsigned short* __restrict__ WTe2, const float* __restrict__ be2,
    unsigned* __restrict__ mbufu)
{
    __shared__ unsigned short h1[64 * 136];
    __shared__ int sl[64], rl[64];
    __shared__ float dl[64], cl[64];
    int tid = threadIdx.x;
    int e0 = blockIdx.x * 64;
    if (tid < 64) {
        sl[tid] = ssend[e0 + tid]; rl[tid] = srecv[e0 + tid];
        dl[tid] = sd[e0 + tid];    cl[tid] = scut[e0 + tid];
    }
    __syncthreads();
    const int wave = tid >> 6, l = tid & 63, l15 = l & 15, l4 = l >> 4;
    const int er = wave * 16 + l15;          // A-fragment edge row
    const int crow = wave * 16 + l4 * 4;     // C-fragment edge row base (+reg)
    const size_t sA = (size_t)sl[er] * 128, rA = (size_t)rl[er] * 128;

    // GEMM1: pair @ Wn1 (K=256: sender 0..127, receiver 128..255)
    f32x4 c1[8] = {};
    #pragma unroll
    for (int ks = 0; ks < 8; ++ks) {
        const unsigned short* ap = (ks < 4) ? (nsb + sA + ks * 32 + l4 * 8)
                                            : (nsb + rA + (ks - 4) * 32 + l4 * 8);
        short8 a = *(const short8*)ap;
        #pragma unroll
        for (int f = 0; f < 8; ++f) {
            short8 b = *(const short8*)(WT1 + (size_t)(f * 16 + l15) * 256 + ks * 32 + l4 * 8);
            c1[f] = __builtin_amdgcn_mfma_f32_16x16x32_bf16(a, b, c1[f], 0, 0, 0);
        }
    }
    #pragma unroll
    for (int fp = 0; fp < 4; ++fp)
        #pragma unroll
        for (int r = 0; r < 4; ++r) {
            float lo = sspf(c1[2 * fp][r]     + bn1[(2 * fp) * 16 + l15]);
            float hi = sspf(c1[2 * fp + 1][r] + bn1[(2 * fp + 1) * 16 + l15]);
            *(unsigned*)&h1[(crow + r) * 136 + (fp * 16 + l15) * 2] = pack2(lo, hi);
        }
    __syncthreads();

    // GEMM2: h1 @ Wn2 (K=128, permuted)
    f32x4 mn[8] = {};
    #pragma unroll
    for (int ks = 0; ks < 4; ++ks) {
        short8 a = *(const short8*)&h1[er * 136 + ks * 32 + l4 * 8];
        #pragma unroll
        for (int f = 0; f < 8; ++f) {
            short8 b = *(const short8*)(WT2 + (size_t)(f * 16 + l15) * 128 + ks * 32 + l4 * 8);
            mn[f] = __builtin_amdgcn_mfma_f32_16x16x32_bf16(a, b, mn[f], 0, 0, 0);
        }
    }
    __syncthreads();   // h1 free for reuse

    // GEMM3: rbf @ We1 (K=64 padded, A computed in registers)
    f32x4 ce[8] = {};
    float dv = dl[er];
    #pragma unroll
    for (int ks = 0; ks < 2; ++ks) {
        short8 a;
        #pragma unroll
        for (int j = 0; j < 8; ++j) {
            int k = ks * 32 + l4 * 8 + j;
            float t = dv - 0.1f * (float)k;
            float v = (k < 50) ? expf(-50.0f * t * t) : 0.0f;
            a[j] = f2bf(v);
        }
        #pragma unroll
        for (int f = 0; f < 8; ++f) {
            short8 b = *(const short8*)(WTe1 + (size_t)(f * 16 + l15) * 64 + ks * 32 + l4 * 8);
            ce[f] = __builtin_amdgcn_mfma_f32_16x16x32_bf16(a, b, ce[f], 0, 0, 0);
        }
    }
    #pragma unroll
    for (int fp = 0; fp < 4; ++fp)
        #pragma unroll
        for (int r = 0; r < 4; ++r) {
            float lo = sspf(ce[2 * fp][r]     + be1[(2 * fp) * 16 + l15]);
            float hi = sspf(ce[2 * fp + 1][r] + be1[(2 * fp + 1) * 16 + l15]);
            *(unsigned*)&h1[(crow + r) * 136 + (fp * 16 + l15) * 2] = pack2(lo, hi);
        }
    __syncthreads();

    // GEMM4: hf @ We2 (K=128, permuted)
    f32x4 gt[8] = {};
    #pragma unroll
    for (int ks = 0; ks < 4; ++ks) {
        short8 a = *(const short8*)&h1[er * 136 + ks * 32 + l4 * 8];
        #pragma unroll
        for (int f = 0; f < 8; ++f) {
            short8 b = *(const short8*)(WTe2 + (size_t)(f * 16 + l15) * 128 + ks * 32 + l4 * 8);
            gt[f] = __builtin_amdgcn_mfma_f32_16x16x32_bf16(a, b, gt[f], 0, 0, 0);
        }
    }

    // messages = (m_node + bn2) * ((gates + be2) * cut)  -> mbuf (sorted order, packed bf16x2)
    #pragma unroll
    for (int r = 0; r < 4; ++r) {
        float cu = cl[crow + r];
        #pragma unroll
        for (int fp = 0; fp < 4; ++fp) {
            float lo = (mn[2 * fp][r]     + bn2[(2 * fp) * 16 + l15])
                     * ((gt[2 * fp][r]     + be2[(2 * fp) * 16 + l15]) * cu);
            float hi = (mn[2 * fp + 1][r] + bn2[(2 * fp + 1) * 16 + l15])
                     * ((gt[2 * fp + 1][r] + be2[(2 * fp + 1) * 16 + l15]) * cu);
            mbufu[(size_t)(e0 + crow + r) * 64 + fp * 16 + l15] = pack2(lo, hi);
        }
    }
}

// ---------------- per-layer: segment-sum + state MLP (MFMA) ----------------

__global__ __launch_bounds__(256) void node_mfma_kernel(
    const unsigned* __restrict__ mbufu, const int* __restrict__ segs,
    const unsigned short* __restrict__ WTs1, const float* __restrict__ bs1,
    const unsigned short* __restrict__ WTs2, const float* __restrict__ bs2,
    float* __restrict__ node_state, unsigned short* __restrict__ nsb,
    float* __restrict__ out_l)
{
    __shared__ unsigned short ah[64 * 136];
    int tid = threadIdx.x;
    int n0 = blockIdx.x * 64;
    {
        int u = tid & 63, ih = tid >> 6;
        for (int i = ih; i < 64; i += 4) {
            int s0 = segs[n0 + i], s1 = segs[n0 + i + 1];
            float aL = 0.0f, aH = 0.0f;
            for (int s = s0; s < s1; ++s) {
                unsigned v = mbufu[(size_t)s * 64 + u];
                aL += bf2f(v & 0xffffu);
                aH += bf2f(v >> 16);
            }
            *(unsigned*)&ah[i * 136 + u * 2] = pack2(aL, aH);
        }
    }
    __syncthreads();
    const int wave = tid >> 6, l = tid & 63, l15 = l & 15, l4 = l >> 4;
    const int er = wave * 16 + l15, crow = wave * 16 + l4 * 4;

    f32x4 cA[8] = {};
    #pragma unroll
    for (int ks = 0; ks < 4; ++ks) {
        short8 a = *(const short8*)&ah[er * 136 + ks * 32 + l4 * 8];
        #pragma unroll
        for (int f = 0; f < 8; ++f) {
            short8 b = *(const short8*)(WTs1 + (size_t)(f * 16 + l15) * 128 + ks * 32 + l4 * 8);
            cA[f] = __builtin_amdgcn_mfma_f32_16x16x32_bf16(a, b, cA[f], 0, 0, 0);
        }
    }
    __syncthreads();
    #pragma unroll
    for (int fp = 0; fp < 4; ++fp)
        #pragma unroll
        for (int r = 0; r < 4; ++r) {
            float lo = sspf(cA[2 * fp][r]     + bs1[(2 * fp) * 16 + l15]);
            float hi = sspf(cA[2 * fp + 1][r] + bs1[(2 * fp + 1) * 16 + l15]);
            *(unsigned*)&ah[(crow + r) * 136 + (fp * 16 + l15) * 2] = pack2(lo, hi);
        }
    __syncthreads();

    f32x4 cB[8] = {};
    #pragma unroll
    for (int ks = 0; ks < 4; ++ks) {
        short8 a = *(const short8*)&ah[er * 136 + ks * 32 + l4 * 8];
        #pragma unroll
        for (int f = 0; f < 8; ++f) {
            short8 b = *(const short8*)(WTs2 + (size_t)(f * 16 + l15) * 128 + ks * 32 + l4 * 8);
            cB[f] = __builtin_amdgcn_mfma_f32_16x16x32_bf16(a, b, cB[f], 0, 0, 0);
        }
    }

    #pragma unroll
    for (int r = 0; r < 4; ++r) {
        int row = n0 + crow + r;
        float vv[8];
        #pragma unroll
        for (int f = 0; f < 8; ++f) {
            int n = f * 16 + l15;
            float v = node_state[(size_t)row * 128 + n] + cB[f][r] + bs2[n];
            node_state[(size_t)row * 128 + n] = v;
            out_l[(size_t)row * 128 + n] = v;
            vv[f] = v;
        }
        #pragma unroll
        for (int fp = 0; fp < 4; ++fp)
            *(unsigned*)&nsb[(size_t)row * 128 + (fp * 16 + l15) * 2] = pack2(vv[2 * fp], vv[2 * fp + 1]);
    }
}

// ---------------- host ----------------

extern "C" void kernel_launch(void* const* d_in, const int* in_sizes, int n_in,
                              void* d_out, int out_size, void* d_ws, size_t ws_size,
                              hipStream_t stream)
{
    const int*   nodes = (const int*)d_in[0];
    const int*   ae    = (const int*)d_in[1];
    const float* aef   = (const float*)d_in[2];
    const float* emb   = (const float*)d_in[5];
    const float* Wn1 = (const float*)d_in[6];  const float* bn1 = (const float*)d_in[7];
    const float* Wn2 = (const float*)d_in[8];  const float* bn2 = (const float*)d_in[9];
    const float* We1 = (const float*)d_in[10]; const float* be1 = (const float*)d_in[11];
    const float* We2 = (const float*)d_in[12]; const float* be2 = (const float*)d_in[13];
    const float* Ws1 = (const float*)d_in[14]; const float* bs1 = (const float*)d_in[15];
    const float* Ws2 = (const float*)d_in[16]; const float* bs2 = (const float*)d_in[17];
    float* out = (float*)d_out;

    char* ws = (char*)d_ws;
    const size_t MB = 1u << 20;
    float*          node_state = (float*)(ws);                    // 8 MB
    unsigned short* nsb        = (unsigned short*)(ws + 8 * MB);  // 4 MB
    unsigned*       mbufu      = (unsigned*)(ws + 12 * MB);       // 64 MB
    int*   ssend  = (int*)(ws + 76 * MB);
    int*   srecv  = (int*)(ws + 77 * MB);
    float* sdv    = (float*)(ws + 78 * MB);
    float* scv    = (float*)(ws + 79 * MB);
    int*   cnt    = (int*)(ws + 80 * MB);
    int*   segs   = (int*)(ws + 80 * MB + 256 * 1024);
    int*   cursor = (int*)(ws + 80 * MB + 512 * 1024);
    unsigned short* WT1  = (unsigned short*)(ws + 81 * MB);                 // 192 KB
    unsigned short* WT2  = (unsigned short*)(ws + 81 * MB + 256 * 1024);    // 96 KB
    unsigned short* WTe1 = (unsigned short*)(ws + 81 * MB + 512 * 1024);    // 48 KB
    unsigned short* WTe2 = (unsigned short*)(ws + 81 * MB + 768 * 1024);    // 96 KB
    unsigned short* WTs1 = (unsigned short*)(ws + 82 * MB);                 // 96 KB
    unsigned short* WTs2 = (unsigned short*)(ws + 82 * MB + 256 * 1024);    // 96 KB

    // one-time prep
    wprep_kernel<<<(LNUM * 128 * 256 + 255) / 256, 256, 0, stream>>>(Wn1, WT1, 256, 256, 1);
    wprep_kernel<<<(LNUM * 128 * 128 + 255) / 256, 256, 0, stream>>>(Wn2, WT2, 128, 128, 1);
    wprep_kernel<<<(LNUM * 128 * 64  + 255) / 256, 256, 0, stream>>>(We1, WTe1, 50, 64, 0);
    wprep_kernel<<<(LNUM * 128 * 128 + 255) / 256, 256, 0, stream>>>(We2, WTe2, 128, 128, 1);
    wprep_kernel<<<(LNUM * 128 * 128 + 255) / 256, 256, 0, stream>>>(Ws1, WTs1, 128, 128, 1);
    wprep_kernel<<<(LNUM * 128 * 128 + 255) / 256, 256, 0, stream>>>(Ws2, WTs2, 128, 128, 1);
    init_nodes_kernel<<<NTOT * 128 / 256, 256, 0, stream>>>(nodes, emb, node_state, nsb);
    hipMemsetAsync(cnt, 0, NTOT * sizeof(int), stream);
    count_kernel<<<ETOT / 256, 256, 0, stream>>>(ae, cnt);
    scan_kernel<<<1, 256, 0, stream>>>(cnt, segs, cursor);
    scatter_kernel<<<ETOT / 256, 256, 0, stream>>>(ae, aef, cursor, ssend, srecv, sdv, scv);

    for (int l = 0; l < LNUM; ++l) {
        edge_mfma_kernel<<<ETOT / 64, 256, 0, stream>>>(
            nsb, ssend, srecv, sdv, scv,
            WT1 + (size_t)l * 128 * 256, bn1 + (size_t)l * 128,
            WT2 + (size_t)l * 128 * 128, bn2 + (size_t)l * 128,
            WTe1 + (size_t)l * 128 * 64, be1 + (size_t)l * 128,
            WTe2 + (size_t)l * 128 * 128, be2 + (size_t)l * 128,
            mbufu);
        node_mfma_kernel<<<NTOT / 64, 256, 0, stream>>>(
            mbufu, segs,
            WTs1 + (size_t)l * 128 * 128, bs1 + (size_t)l * 128,
            WTs2 + (size_t)l * 128 * 128, bs2 + (size_t)l * 128,
            node_state, nsb, out + (size_t)l * NTOT * 128);
    }
}

// Round 3
// 963.489 us; speedup vs baseline: 3.1938x; 1.3352x over previous
//
#include <hip/hip_runtime.h>
#include <hip/hip_bf16.h>
#include <math.h>

#define BQ 8
#define NPER 2048
#define EPER 32768
#define NTOT (BQ * NPER)          // 16384
#define ETOT (BQ * EPER)          // 262144
#define HDIM 128
#define LNUM 3

typedef __attribute__((ext_vector_type(8))) short short8;
typedef __attribute__((ext_vector_type(4))) float f32x4;

__device__ __forceinline__ short f2bf(float x) {
    union { float f; unsigned u; } v; v.f = x;
    unsigned r = v.u + 0x7fffu + ((v.u >> 16) & 1u);
    return (short)(r >> 16);
}
__device__ __forceinline__ float bf2f(unsigned hi16) {
    union { unsigned u; float f; } v; v.u = hi16 << 16; return v.f;
}
__device__ __forceinline__ unsigned pack2(float a, float b) {
    return (unsigned)(unsigned short)f2bf(a) | ((unsigned)(unsigned short)f2bf(b) << 16);
}
__device__ __forceinline__ float sspf(float x) {
    return 0.6931471805599453f * (log2f(1.0f + exp2f(x * 1.4426950408889634f)) - 1.0f);
}

// ---- LDS access helpers (XOR-swizzled rows; rows are 256B for act tiles, 128B for B tiles)
__device__ __forceinline__ short8 ldsA(const unsigned short* t, int row, int pos) {
    // act tile [*][128] shorts; pos = short index 0..127 (16B-aligned groups)
    return *(const short8*)((const char*)t + row * 256 + ((pos * 2) ^ ((row & 7) << 4)));
}
__device__ __forceinline__ short8 ldsB(const unsigned short* t, int n, int pos) {
    // B tile [128][64] shorts; pos = short index 0..63
    return *(const short8*)((const char*)t + n * 128 + ((pos * 2) ^ ((n & 7) << 4)));
}
__device__ __forceinline__ void actW(unsigned short* t, int row, int dw, unsigned v) {
    // write dword dw (feature pair) of act tile row
    *(unsigned*)((char*)t + row * 256 + ((dw * 4) ^ ((row & 7) << 4))) = v;
}
// cooperative stage of a [128 n][64 k] bf16 B chunk into swizzled LDS
__device__ __forceinline__ void stage_b64(const unsigned short* __restrict__ src, int strideK, int kbase,
                                          unsigned short* __restrict__ Bs, int tid) {
    #pragma unroll
    for (int it = 0; it < 8; ++it) {
        int i = it * 256 + tid;            // 2048 x 8B
        int n = i >> 4, kd2 = i & 15;
        uint2 v = *(const uint2*)&src[(size_t)n * strideK + kbase + kd2 * 4];
        *(uint2*)((char*)Bs + n * 128 + ((kd2 * 8) ^ ((n & 7) << 4))) = v;
    }
}

// ---------------- once-per-launch prep ----------------

__global__ __launch_bounds__(256) void wprep_kernel(
    const float* __restrict__ W, unsigned short* __restrict__ WT,
    int K, int KP, int doperm)
{
    int idx = blockIdx.x * 256 + threadIdx.x;
    int total = LNUM * 128 * KP;
    if (idx >= total) return;
    int l = idx / (128 * KP);
    int rem = idx - l * (128 * KP);
    int n = rem / KP;
    int p = rem - n * KP;
    int k;
    if (doperm) {
        int half = p >> 7, pp = p & 127;
        k = (half << 7) | ((pp >> 5) << 5) | ((pp & 1) << 4) | ((pp & 31) >> 1);
    } else k = p;
    float v = (k < K) ? W[((size_t)l * K + k) * 128 + n] : 0.0f;
    WT[idx] = (unsigned short)f2bf(v);
}

__global__ __launch_bounds__(256) void init_nodes_kernel(
    const int* __restrict__ nodes, const float* __restrict__ emb,
    float* __restrict__ node_state, unsigned short* __restrict__ nsb)
{
    int idx = blockIdx.x * 256 + threadIdx.x;
    int n = idx >> 7, p = idx & 127;
    int j = ((p >> 5) << 5) | ((p & 1) << 4) | ((p & 31) >> 1);
    float v = emb[(size_t)nodes[n] * 128 + j];
    nsb[idx] = (unsigned short)f2bf(v);
    node_state[(n << 7) + j] = v;
}

__global__ __launch_bounds__(256) void count_kernel(const int* __restrict__ ae, int* __restrict__ cnt)
{
    int g = blockIdx.x * 256 + threadIdx.x;
    int b = g >> 15;
    atomicAdd(&cnt[ae[2 * g + 1] + b * NPER], 1);
}

__global__ __launch_bounds__(256) void scan_kernel(
    const int* __restrict__ cnt, int* __restrict__ segs, int* __restrict__ cursor)
{
    __shared__ int part[256];
    int t = threadIdx.x;
    int base = t * 64;
    int s = 0;
    for (int i = 0; i < 64; ++i) s += cnt[base + i];
    part[t] = s;
    __syncthreads();
    for (int ofs = 1; ofs < 256; ofs <<= 1) {
        int v = part[t];
        int add = (t >= ofs) ? part[t - ofs] : 0;
        __syncthreads();
        part[t] = v + add;
        __syncthreads();
    }
    int run = part[t] - s;
    for (int i = 0; i < 64; ++i) {
        segs[base + i] = run;
        cursor[base + i] = run;
        run += cnt[base + i];
    }
    if (t == 255) segs[NTOT] = run;
}

__global__ __launch_bounds__(256) void scatter_kernel(
    const int* __restrict__ ae, const float* __restrict__ aef, int* __restrict__ cursor,
    int* __restrict__ ssend, int* __restrict__ srecv,
    float* __restrict__ sdv, float* __restrict__ scv)
{
    int g = blockIdx.x * 256 + threadIdx.x;
    int b = g >> 15;
    int sn = ae[2 * g] + b * NPER, rv = ae[2 * g + 1] + b * NPER;
    int pos = atomicAdd(&cursor[rv], 1);
    ssend[pos] = sn; srecv[pos] = rv;
    float dd = aef[g];
    sdv[pos] = dd;
    scv[pos] = 1.0f - 1.0f / (1.0f + expf(-5.0f * (dd - 3.5f)));
}

// ---------------- per-layer: edge messages (MFMA, LDS-staged B, 2 tiles/wave) ----------------

#define MFMA(A, B, C) __builtin_amdgcn_mfma_f32_16x16x32_bf16(A, B, C, 0, 0, 0)

__global__ __launch_bounds__(256) void edge_mfma_kernel(
    const unsigned short* __restrict__ nsb,
    const int* __restrict__ ssend, const int* __restrict__ srecv,
    const float* __restrict__ sd, const float* __restrict__ scut,
    const unsigned short* __restrict__ WT1, const float* __restrict__ bn1,
    const unsigned short* __restrict__ WT2, const float* __restrict__ bn2,
    const unsigned short* __restrict__ WTe1, const float* __restrict__ be1,
    const unsigned short* __restrict__ WTe2, const float* __restrict__ be2,
    unsigned* __restrict__ mbufu)
{
    __shared__ unsigned short h1[128 * 128];   // 32 KB act tile (swizzled)
    __shared__ unsigned short Bs[128 * 64];    // 16 KB weight chunk (swizzled)
    __shared__ int sl[128], rl[128];
    __shared__ float dl[128], cl[128];

    int tid = threadIdx.x;
    int e0 = blockIdx.x * 128;
    if (tid < 128) {
        sl[tid] = ssend[e0 + tid]; rl[tid] = srecv[e0 + tid];
        dl[tid] = sd[e0 + tid];    cl[tid] = scut[e0 + tid];
    }
    __syncthreads();
    const int wave = tid >> 6, l = tid & 63, l15 = l & 15, l4 = l >> 4;
    const int er0 = wave * 32 + l15;       // tile0 A-row (edge idx in block)
    const int er1 = er0 + 16;              // tile1

    // ---- GEMM1: pair @ Wn1  (K=256: chunks 0,1 = sender, 2,3 = receiver)
    f32x4 cA[8] = {}, cB[8] = {};
    #pragma unroll
    for (int c = 0; c < 4; ++c) {
        stage_b64(WT1, 256, c * 64, Bs, tid);
        __syncthreads();
        const int r0 = (c < 2) ? sl[er0] : rl[er0];
        const int r1 = (c < 2) ? sl[er1] : rl[er1];
        const int base = (c & 1) * 64;
        short8 a[2][2];
        #pragma unroll
        for (int ks = 0; ks < 2; ++ks) {
            a[ks][0] = *(const short8*)(nsb + (size_t)r0 * 128 + base + ks * 32 + l4 * 8);
            a[ks][1] = *(const short8*)(nsb + (size_t)r1 * 128 + base + ks * 32 + l4 * 8);
        }
        #pragma unroll
        for (int ks = 0; ks < 2; ++ks)
            #pragma unroll
            for (int f = 0; f < 8; ++f) {
                short8 b = ldsB(Bs, f * 16 + l15, ks * 32 + l4 * 8);
                cA[f] = MFMA(a[ks][0], b, cA[f]);
                cB[f] = MFMA(a[ks][1], b, cB[f]);
            }
        __syncthreads();
    }
    #pragma unroll
    for (int fp = 0; fp < 4; ++fp)
        #pragma unroll
        for (int r = 0; r < 4; ++r) {
            int row0 = wave * 32 + l4 * 4 + r;
            actW(h1, row0, fp * 16 + l15,
                 pack2(sspf(cA[2 * fp][r]     + bn1[(2 * fp) * 16 + l15]),
                       sspf(cA[2 * fp + 1][r] + bn1[(2 * fp + 1) * 16 + l15])));
            actW(h1, row0 + 16, fp * 16 + l15,
                 pack2(sspf(cB[2 * fp][r]     + bn1[(2 * fp) * 16 + l15]),
                       sspf(cB[2 * fp + 1][r] + bn1[(2 * fp + 1) * 16 + l15])));
        }
    __syncthreads();

    // ---- GEMM2: h1 @ Wn2 (K=128, 2 chunks)
    f32x4 m0[8] = {}, m1[8] = {};
    #pragma unroll
    for (int c = 0; c < 2; ++c) {
        stage_b64(WT2, 128, c * 64, Bs, tid);
        __syncthreads();
        #pragma unroll
        for (int ks = 0; ks < 2; ++ks) {
            int pos = c * 64 + ks * 32 + l4 * 8;
            short8 a0 = ldsA(h1, er0, pos);
            short8 a1 = ldsA(h1, er1, pos);
            #pragma unroll
            for (int f = 0; f < 8; ++f) {
                short8 b = ldsB(Bs, f * 16 + l15, ks * 32 + l4 * 8);
                m0[f] = MFMA(a0, b, m0[f]);
                m1[f] = MFMA(a1, b, m1[f]);
            }
        }
        __syncthreads();
    }
    // pack m_node + bias to bf16 (frees 32 VGPRs)
    unsigned mnp0[16], mnp1[16];
    #pragma unroll
    for (int fp = 0; fp < 4; ++fp)
        #pragma unroll
        for (int r = 0; r < 4; ++r) {
            mnp0[fp * 4 + r] = pack2(m0[2 * fp][r]     + bn2[(2 * fp) * 16 + l15],
                                     m0[2 * fp + 1][r] + bn2[(2 * fp + 1) * 16 + l15]);
            mnp1[fp * 4 + r] = pack2(m1[2 * fp][r]     + bn2[(2 * fp) * 16 + l15],
                                     m1[2 * fp + 1][r] + bn2[(2 * fp + 1) * 16 + l15]);
        }

    // ---- GEMM3: rbf(d) @ We1 (K=64, 1 chunk; A computed in registers)
    f32x4 e0a[8] = {}, e1a[8] = {};
    stage_b64(WTe1, 64, 0, Bs, tid);
    __syncthreads();
    {
        float dv0 = dl[er0], dv1 = dl[er1];
        #pragma unroll
        for (int ks = 0; ks < 2; ++ks) {
            short8 a0, a1;
            #pragma unroll
            for (int j = 0; j < 8; ++j) {
                int k = ks * 32 + l4 * 8 + j;
                float t0 = dv0 - 0.1f * (float)k;
                float t1 = dv1 - 0.1f * (float)k;
                a0[j] = (k < 50) ? f2bf(expf(-50.0f * t0 * t0)) : (short)0;
                a1[j] = (k < 50) ? f2bf(expf(-50.0f * t1 * t1)) : (short)0;
            }
            #pragma unroll
            for (int f = 0; f < 8; ++f) {
                short8 b = ldsB(Bs, f * 16 + l15, ks * 32 + l4 * 8);
                e0a[f] = MFMA(a0, b, e0a[f]);
                e1a[f] = MFMA(a1, b, e1a[f]);
            }
        }
    }
    __syncthreads();
    #pragma unroll
    for (int fp = 0; fp < 4; ++fp)
        #pragma unroll
        for (int r = 0; r < 4; ++r) {
            int row0 = wave * 32 + l4 * 4 + r;
            actW(h1, row0, fp * 16 + l15,
                 pack2(sspf(e0a[2 * fp][r]     + be1[(2 * fp) * 16 + l15]),
                       sspf(e0a[2 * fp + 1][r] + be1[(2 * fp + 1) * 16 + l15])));
            actW(h1, row0 + 16, fp * 16 + l15,
                 pack2(sspf(e1a[2 * fp][r]     + be1[(2 * fp) * 16 + l15]),
                       sspf(e1a[2 * fp + 1][r] + be1[(2 * fp + 1) * 16 + l15])));
        }
    __syncthreads();

    // ---- GEMM4: hfilt @ We2 (K=128, 2 chunks)
    f32x4 g0[8] = {}, g1[8] = {};
    #pragma unroll
    for (int c = 0; c < 2; ++c) {
        stage_b64(WTe2, 128, c * 64, Bs, tid);
        __syncthreads();
        #pragma unroll
        for (int ks = 0; ks < 2; ++ks) {
            int pos = c * 64 + ks * 32 + l4 * 8;
            short8 a0 = ldsA(h1, er0, pos);
            short8 a1 = ldsA(h1, er1, pos);
            #pragma unroll
            for (int f = 0; f < 8; ++f) {
                short8 b = ldsB(Bs, f * 16 + l15, ks * 32 + l4 * 8);
                g0[f] = MFMA(a0, b, g0[f]);
                g1[f] = MFMA(a1, b, g1[f]);
            }
        }
        __syncthreads();
    }

    // ---- combine: messages = (m_node+bn2) * ((gates+be2)*cut) -> mbuf (bf16x2)
    #pragma unroll
    for (int r = 0; r < 4; ++r) {
        int row0 = wave * 32 + l4 * 4 + r;
        float cu0 = cl[row0], cu1 = cl[row0 + 16];
        #pragma unroll
        for (int fp = 0; fp < 4; ++fp) {
            float bl = be2[(2 * fp) * 16 + l15], bh = be2[(2 * fp + 1) * 16 + l15];
            unsigned v0 = mnp0[fp * 4 + r], v1 = mnp1[fp * 4 + r];
            float lo0 = bf2f(v0 & 0xffffu) * ((g0[2 * fp][r] + bl) * cu0);
            float hi0 = bf2f(v0 >> 16)     * ((g0[2 * fp + 1][r] + bh) * cu0);
            float lo1 = bf2f(v1 & 0xffffu) * ((g1[2 * fp][r] + bl) * cu1);
            float hi1 = bf2f(v1 >> 16)     * ((g1[2 * fp + 1][r] + bh) * cu1);
            mbufu[(size_t)(e0 + row0) * 64 + fp * 16 + l15] = pack2(lo0, hi0);
            mbufu[(size_t)(e0 + row0 + 16) * 64 + fp * 16 + l15] = pack2(lo1, hi1);
        }
    }
}

// ---------------- per-layer: segment-sum + state MLP (MFMA) ----------------

__global__ __launch_bounds__(256) void node_mfma_kernel(
    const unsigned* __restrict__ mbufu, const int* __restrict__ segs,
    const unsigned short* __restrict__ WTs1, const float* __restrict__ bs1,
    const unsigned short* __restrict__ WTs2, const float* __restrict__ bs2,
    float* __restrict__ node_state, unsigned short* __restrict__ nsb,
    float* __restrict__ out_l)
{
    __shared__ unsigned short ah[64 * 128];   // 16 KB act tile (swizzled)
    __shared__ unsigned short Bs[128 * 64];   // 16 KB weight chunk
    int tid = threadIdx.x;
    int n0 = blockIdx.x * 64;
    {
        int u = tid & 63, ih = tid >> 6;
        for (int i = ih; i < 64; i += 4) {
            int s0 = segs[n0 + i], s1 = segs[n0 + i + 1];
            float aL = 0.0f, aH = 0.0f;
            for (int s = s0; s < s1; ++s) {
                unsigned v = mbufu[(size_t)s * 64 + u];
                aL += bf2f(v & 0xffffu);
                aH += bf2f(v >> 16);
            }
            *(unsigned*)((char*)ah + i * 256 + ((u * 4) ^ ((i & 7) << 4))) = pack2(aL, aH);
        }
    }
    __syncthreads();
    const int wave = tid >> 6, l = tid & 63, l15 = l & 15, l4 = l >> 4;
    const int er = wave * 16 + l15, crow = wave * 16 + l4 * 4;

    f32x4 c1[8] = {};
    #pragma unroll
    for (int c = 0; c < 2; ++c) {
        stage_b64(WTs1, 128, c * 64, Bs, tid);
        __syncthreads();
        #pragma unroll
        for (int ks = 0; ks < 2; ++ks) {
            short8 a = ldsA(ah, er, c * 64 + ks * 32 + l4 * 8);
            #pragma unroll
            for (int f = 0; f < 8; ++f) {
                short8 b = ldsB(Bs, f * 16 + l15, ks * 32 + l4 * 8);
                c1[f] = MFMA(a, b, c1[f]);
            }
        }
        __syncthreads();
    }
    #pragma unroll
    for (int fp = 0; fp < 4; ++fp)
        #pragma unroll
        for (int r = 0; r < 4; ++r)
            actW(ah, crow + r, fp * 16 + l15,
                 pack2(sspf(c1[2 * fp][r]     + bs1[(2 * fp) * 16 + l15]),
                       sspf(c1[2 * fp + 1][r] + bs1[(2 * fp + 1) * 16 + l15])));
    __syncthreads();

    f32x4 c2[8] = {};
    #pragma unroll
    for (int c = 0; c < 2; ++c) {
        stage_b64(WTs2, 128, c * 64, Bs, tid);
        __syncthreads();
        #pragma unroll
        for (int ks = 0; ks < 2; ++ks) {
            short8 a = ldsA(ah, er, c * 64 + ks * 32 + l4 * 8);
            #pragma unroll
            for (int f = 0; f < 8; ++f) {
                short8 b = ldsB(Bs, f * 16 + l15, ks * 32 + l4 * 8);
                c2[f] = MFMA(a, b, c2[f]);
            }
        }
        __syncthreads();
    }

    #pragma unroll
    for (int r = 0; r < 4; ++r) {
        int row = n0 + crow + r;
        float vv[8];
        #pragma unroll
        for (int f = 0; f < 8; ++f) {
            int n = f * 16 + l15;
            float v = node_state[(size_t)row * 128 + n] + c2[f][r] + bs2[n];
            node_state[(size_t)row * 128 + n] = v;
            out_l[(size_t)row * 128 + n] = v;
            vv[f] = v;
        }
        #pragma unroll
        for (int fp = 0; fp < 4; ++fp)
            *(unsigned*)&nsb[(size_t)row * 128 + (fp * 16 + l15) * 2] = pack2(vv[2 * fp], vv[2 * fp + 1]);
    }
}

// ---------------- host ----------------

extern "C" void kernel_launch(void* const* d_in, const int* in_sizes, int n_in,
                              void* d_out, int out_size, void* d_ws, size_t ws_size,
                              hipStream_t stream)
{
    const int*   nodes = (const int*)d_in[0];
    const int*   ae    = (const int*)d_in[1];
    const float* aef   = (const float*)d_in[2];
    const float* emb   = (const float*)d_in[5];
    const float* Wn1 = (const float*)d_in[6];  const float* bn1 = (const float*)d_in[7];
    const float* Wn2 = (const float*)d_in[8];  const float* bn2 = (const float*)d_in[9];
    const float* We1 = (const float*)d_in[10]; const float* be1 = (const float*)d_in[11];
    const float* We2 = (const float*)d_in[12]; const float* be2 = (const float*)d_in[13];
    const float* Ws1 = (const float*)d_in[14]; const float* bs1 = (const float*)d_in[15];
    const float* Ws2 = (const float*)d_in[16]; const float* bs2 = (const float*)d_in[17];
    float* out = (float*)d_out;

    char* ws = (char*)d_ws;
    const size_t MB = 1u << 20;
    float*          node_state = (float*)(ws);                    // 8 MB
    unsigned short* nsb        = (unsigned short*)(ws + 8 * MB);  // 4 MB
    unsigned*       mbufu      = (unsigned*)(ws + 12 * MB);       // 64 MB
    int*   ssend  = (int*)(ws + 76 * MB);
    int*   srecv  = (int*)(ws + 77 * MB);
    float* sdv    = (float*)(ws + 78 * MB);
    float* scv    = (float*)(ws + 79 * MB);
    int*   cnt    = (int*)(ws + 80 * MB);
    int*   segs   = (int*)(ws + 80 * MB + 256 * 1024);
    int*   cursor = (int*)(ws + 80 * MB + 512 * 1024);
    unsigned short* WT1  = (unsigned short*)(ws + 81 * MB);
    unsigned short* WT2  = (unsigned short*)(ws + 81 * MB + 256 * 1024);
    unsigned short* WTe1 = (unsigned short*)(ws + 81 * MB + 512 * 1024);
    unsigned short* WTe2 = (unsigned short*)(ws + 81 * MB + 768 * 1024);
    unsigned short* WTs1 = (unsigned short*)(ws + 82 * MB);
    unsigned short* WTs2 = (unsigned short*)(ws + 82 * MB + 256 * 1024);

    wprep_kernel<<<(LNUM * 128 * 256 + 255) / 256, 256, 0, stream>>>(Wn1, WT1, 256, 256, 1);
    wprep_kernel<<<(LNUM * 128 * 128 + 255) / 256, 256, 0, stream>>>(Wn2, WT2, 128, 128, 1);
    wprep_kernel<<<(LNUM * 128 * 64  + 255) / 256, 256, 0, stream>>>(We1, WTe1, 50, 64, 0);
    wprep_kernel<<<(LNUM * 128 * 128 + 255) / 256, 256, 0, stream>>>(We2, WTe2, 128, 128, 1);
    wprep_kernel<<<(LNUM * 128 * 128 + 255) / 256, 256, 0, stream>>>(Ws1, WTs1, 128, 128, 1);
    wprep_kernel<<<(LNUM * 128 * 128 + 255) / 256, 256, 0, stream>>>(Ws2, WTs2, 128, 128, 1);
    init_nodes_kernel<<<NTOT * 128 / 256, 256, 0, stream>>>(nodes, emb, node_state, nsb);
    hipMemsetAsync(cnt, 0, NTOT * sizeof(int), stream);
    count_kernel<<<ETOT / 256, 256, 0, stream>>>(ae, cnt);
    scan_kernel<<<1, 256, 0, stream>>>(cnt, segs, cursor);
    scatter_kernel<<<ETOT / 256, 256, 0, stream>>>(ae, aef, cursor, ssend, srecv, sdv, scv);

    for (int l = 0; l < LNUM; ++l) {
        edge_mfma_kernel<<<ETOT / 128, 256, 0, stream>>>(
            nsb, ssend, srecv, sdv, scv,
            WT1 + (size_t)l * 128 * 256, bn1 + (size_t)l * 128,
            WT2 + (size_t)l * 128 * 128, bn2 + (size_t)l * 128,
            WTe1 + (size_t)l * 128 * 64, be1 + (size_t)l * 128,
            WTe2 + (size_t)l * 128 * 128, be2 + (size_t)l * 128,
            mbufu);
        node_mfma_kernel<<<NTOT / 64, 256, 0, stream>>>(
            mbufu, segs,
            WTs1 + (size_t)l * 128 * 128, bs1 + (size_t)l * 128,
            WTs2 + (size_t)l * 128 * 128, bs2 + (size_t)l * 128,
            node_state, nsb, out + (size_t)l * NTOT * 128);
    }
}

// Round 5
// 621.627 us; speedup vs baseline: 4.9503x; 1.5499x over previous
//
#include <hip/hip_runtime.h>
#include <hip/hip_bf16.h>
#include <math.h>

#define BQ 8
#define NPER 2048
#define EPER 32768
#define NTOT (BQ * NPER)          // 16384
#define ETOT (BQ * EPER)          // 262144
#define HDIM 128
#define LNUM 3

typedef __attribute__((ext_vector_type(8))) short short8;
typedef __attribute__((ext_vector_type(4))) float f32x4;

__device__ __forceinline__ short f2bf(float x) {
    union { float f; unsigned u; } v; v.f = x;
    unsigned r = v.u + 0x7fffu + ((v.u >> 16) & 1u);
    return (short)(r >> 16);
}
// paired f32 -> packed bf16x2 (compiler emits v_cvt_pk_bf16_f32 — m240)
__device__ __forceinline__ unsigned pk2(float lo, float hi) {
    union { __hip_bfloat162 h; unsigned u; } v;
    float2 f; f.x = lo; f.y = hi;
    v.h = __float22bfloat162_rn(f);
    return v.u;
}
__device__ __forceinline__ float bflo(unsigned v) {
    union { unsigned u; float f; } x; x.u = v << 16; return x.f;
}
__device__ __forceinline__ float bfhi(unsigned v) {
    union { unsigned u; float f; } x; x.u = v & 0xffff0000u; return x.f;
}
__device__ __forceinline__ float sspf(float x) {
    return 0.6931471805599453f * (log2f(1.0f + exp2f(x * 1.4426950408889634f)) - 1.0f);
}

// ---- LDS helpers (XOR-swizzled; act rows 256B, B rows 128B) ----
__device__ __forceinline__ short8 ldsA(const unsigned short* t, int row, int pos) {
    return *(const short8*)((const char*)t + row * 256 + ((pos * 2) ^ ((row & 7) << 4)));
}
__device__ __forceinline__ short8 ldsB(const unsigned short* t, int n, int pos) {
    return *(const short8*)((const char*)t + n * 128 + ((pos * 2) ^ ((n & 7) << 4)));
}
__device__ __forceinline__ void actW(unsigned short* t, int row, int dw, unsigned v) {
    *(unsigned*)((char*)t + row * 256 + ((dw * 4) ^ ((row & 7) << 4))) = v;
}

// ---- T14 async-STAGE split: load-early (regs, LINEAR source), write-late (swizzled LDS) ----
// Stages a [128 n][64 k-shorts] 16KB B-panel chunk.  (rule #21: swizzle on write+read only)
struct StageReg { uint4 v[4]; };
__device__ __forceinline__ void stage_load(StageReg& s, const unsigned short* __restrict__ src,
                                           int strideK, int kbase, int tid) {
    #pragma unroll
    for (int it = 0; it < 4; ++it) {
        int u = it * 256 + tid;          // 16B unit
        int n = u >> 3, kd8 = u & 7;     // LINEAR source
        s.v[it] = *(const uint4*)&src[(size_t)n * strideK + kbase + kd8 * 8];
    }
}
__device__ __forceinline__ void stage_write(const StageReg& s, unsigned short* Bs, int tid) {
    #pragma unroll
    for (int it = 0; it < 4; ++it) {
        int u = it * 256 + tid;
        int n = u >> 3;
        *(uint4*)((char*)Bs + ((u * 16) ^ ((n & 7) << 4))) = s.v[it];
    }
}
// legacy 8B-unit stager (node kernel)
__device__ __forceinline__ void stage_b64(const unsigned short* __restrict__ src, int strideK, int kbase,
                                          unsigned short* __restrict__ Bs, int tid) {
    #pragma unroll
    for (int it = 0; it < 8; ++it) {
        int i = it * 256 + tid;
        int n = i >> 4, kd2 = i & 15;
        uint2 v = *(const uint2*)&src[(size_t)n * strideK + kbase + kd2 * 4];
        *(uint2*)((char*)Bs + n * 128 + ((kd2 * 8) ^ ((n & 7) << 4))) = v;
    }
}

#define MFMA(A, B, C) __builtin_amdgcn_mfma_f32_16x16x32_bf16(A, B, C, 0, 0, 0)

// ---------------- once-per-launch prep ----------------

__global__ __launch_bounds__(256) void wprep_kernel(
    const float* __restrict__ W, unsigned short* __restrict__ WT,
    int K, int KP, int doperm)
{
    int idx = blockIdx.x * 256 + threadIdx.x;
    int total = LNUM * 128 * KP;
    if (idx >= total) return;
    int l = idx / (128 * KP);
    int rem = idx - l * (128 * KP);
    int n = rem / KP;
    int p = rem - n * KP;
    int k;
    if (doperm) {
        int half = p >> 7, pp = p & 127;
        k = (half << 7) | ((pp >> 5) << 5) | ((pp & 1) << 4) | ((pp & 31) >> 1);
    } else k = p;
    float v = (k < K) ? W[((size_t)l * K + k) * 128 + n] : 0.0f;
    WT[idx] = (unsigned short)f2bf(v);
}

__global__ __launch_bounds__(256) void init_nodes_kernel(
    const int* __restrict__ nodes, const float* __restrict__ emb,
    float* __restrict__ node_state, unsigned short* __restrict__ nsb)
{
    int idx = blockIdx.x * 256 + threadIdx.x;
    int n = idx >> 7, p = idx & 127;
    int j = ((p >> 5) << 5) | ((p & 1) << 4) | ((p & 31) >> 1);
    float v = emb[(size_t)nodes[n] * 128 + j];
    nsb[idx] = (unsigned short)f2bf(v);
    node_state[(n << 7) + j] = v;
}

__global__ __launch_bounds__(256) void count_kernel(const int* __restrict__ ae, int* __restrict__ cnt)
{
    int g = blockIdx.x * 256 + threadIdx.x;
    int b = g >> 15;
    atomicAdd(&cnt[ae[2 * g + 1] + b * NPER], 1);
}

__global__ __launch_bounds__(256) void scan_kernel(
    const int* __restrict__ cnt, int* __restrict__ segs, int* __restrict__ cursor)
{
    __shared__ int part[256];
    int t = threadIdx.x;
    int base = t * 64;
    int s = 0;
    for (int i = 0; i < 64; ++i) s += cnt[base + i];
    part[t] = s;
    __syncthreads();
    for (int ofs = 1; ofs < 256; ofs <<= 1) {
        int v = part[t];
        int add = (t >= ofs) ? part[t - ofs] : 0;
        __syncthreads();
        part[t] = v + add;
        __syncthreads();
    }
    int run = part[t] - s;
    for (int i = 0; i < 64; ++i) {
        segs[base + i] = run;
        cursor[base + i] = run;
        run += cnt[base + i];
    }
    if (t == 255) segs[NTOT] = run;
}

__global__ __launch_bounds__(256) void scatter_kernel(
    const int* __restrict__ ae, const float* __restrict__ aef, int* __restrict__ cursor,
    int* __restrict__ ssend, int* __restrict__ srecv,
    float* __restrict__ sdv, float* __restrict__ scv)
{
    int g = blockIdx.x * 256 + threadIdx.x;
    int b = g >> 15;
    int sn = ae[2 * g] + b * NPER, rv = ae[2 * g + 1] + b * NPER;
    int pos = atomicAdd(&cursor[rv], 1);
    ssend[pos] = sn; srecv[pos] = rv;
    float dd = aef[g];
    sdv[pos] = dd;
    scv[pos] = 1.0f - 1.0f / (1.0f + expf(-5.0f * (dd - 3.5f)));
}

// ---------------- per-layer: node projections (replaces edge GEMM1) ----------------
// sproj = state @ Wn1_top + bn1 ; rproj = state @ Wn1_bot   (bf16-pair dwords, dw = fp*16+l15)

__global__ __launch_bounds__(256, 3) void nodeproj_kernel(
    const unsigned short* __restrict__ nsb,
    const unsigned short* __restrict__ WT1, const float* __restrict__ bn1,
    unsigned* __restrict__ sprojP, unsigned* __restrict__ rprojP)
{
    __shared__ unsigned short Bs[2][64 * 128];
    const int tid = threadIdx.x;
    const int n0 = blockIdx.x * 64;
    const int wv = tid >> 6, l = tid & 63, l15 = l & 15, l4 = l >> 4;
    const int er = wv * 16 + l15, crow = wv * 16 + l4 * 4;

    short8 a[4];
    #pragma unroll
    for (int ks = 0; ks < 4; ++ks)
        a[ks] = *(const short8*)&nsb[(size_t)(n0 + er) * 128 + ks * 32 + l4 * 8];

    StageReg sr;
    stage_load(sr, WT1, 256, 0, tid);
    stage_write(sr, Bs[0], tid);
    __syncthreads();

    f32x4 cs[8] = {}, cr[8] = {};
    // P1: prefetch k64 -> Bs[1]; sproj chunk0
    stage_load(sr, WT1, 256, 64, tid);
    #pragma unroll
    for (int ks = 0; ks < 2; ++ks)
        #pragma unroll
        for (int f = 0; f < 8; ++f)
            cs[f] = MFMA(a[ks], ldsB(Bs[0], f * 16 + l15, ks * 32 + l4 * 8), cs[f]);
    stage_write(sr, Bs[1], tid);
    __syncthreads();
    // P2: prefetch k128 -> Bs[0]; sproj chunk1
    stage_load(sr, WT1, 256, 128, tid);
    #pragma unroll
    for (int ks = 0; ks < 2; ++ks)
        #pragma unroll
        for (int f = 0; f < 8; ++f)
            cs[f] = MFMA(a[2 + ks], ldsB(Bs[1], f * 16 + l15, ks * 32 + l4 * 8), cs[f]);
    stage_write(sr, Bs[0], tid);
    __syncthreads();
    // P3: prefetch k192 -> Bs[1]; rproj chunk0
    stage_load(sr, WT1, 256, 192, tid);
    #pragma unroll
    for (int ks = 0; ks < 2; ++ks)
        #pragma unroll
        for (int f = 0; f < 8; ++f)
            cr[f] = MFMA(a[ks], ldsB(Bs[0], f * 16 + l15, ks * 32 + l4 * 8), cr[f]);
    stage_write(sr, Bs[1], tid);
    __syncthreads();
    // P4: rproj chunk1
    #pragma unroll
    for (int ks = 0; ks < 2; ++ks)
        #pragma unroll
        for (int f = 0; f < 8; ++f)
            cr[f] = MFMA(a[2 + ks], ldsB(Bs[1], f * 16 + l15, ks * 32 + l4 * 8), cr[f]);

    #pragma unroll
    for (int fp = 0; fp < 4; ++fp) {
        float bl = bn1[fp * 32 + l15], bh = bn1[fp * 32 + 16 + l15];
        #pragma unroll
        for (int r = 0; r < 4; ++r) {
            size_t o = (size_t)(n0 + crow + r) * 64 + fp * 16 + l15;
            sprojP[o] = pk2(cs[2 * fp][r] + bl, cs[2 * fp + 1][r] + bh);
            rprojP[o] = pk2(cr[2 * fp][r], cr[2 * fp + 1][r]);
        }
    }
}

// ---------------- per-layer: edge messages ----------------

__global__ __launch_bounds__(256, 2) void edge_mfma_kernel(
    const unsigned* __restrict__ sprojP, const unsigned* __restrict__ rprojP,
    const int* __restrict__ ssend, const int* __restrict__ srecv,
    const float* __restrict__ sdv, const float* __restrict__ scv,
    const unsigned short* __restrict__ WT2, const float* __restrict__ bn2,
    const unsigned short* __restrict__ WTe1, const float* __restrict__ be1,
    const unsigned short* __restrict__ WTe2, const float* __restrict__ be2,
    unsigned* __restrict__ mbufu)
{
    __shared__ unsigned short h1[128 * 128];   // 32 KB act tile (swizzled 256B rows)
    __shared__ unsigned short Bs[2][64 * 128]; // 2 x 16 KB B panels
    const int tid = threadIdx.x;
    const int e0 = blockIdx.x * 128;
    const int wv = tid >> 6, l = tid & 63, l15 = l & 15, l4 = l >> 4;
    const int er0 = wv * 32 + l15, er1 = er0 + 16;
    const int crow = wv * 32 + l4 * 4;

    StageReg sr;
    // ---- P0: prefetch WT2 k0 -> Bs[0]; h1 = ssp(sproj[s] + rproj[r])
    stage_load(sr, WT2, 128, 0, tid);
    #pragma unroll 4
    for (int it = 0; it < 32; ++it) {
        int e = wv * 32 + it;
        int sn = ssend[e0 + e], rn = srecv[e0 + e];
        unsigned sp = sprojP[(size_t)sn * 64 + l];
        unsigned rp = rprojP[(size_t)rn * 64 + l];
        actW(h1, e, l, pk2(sspf(bflo(sp) + bflo(rp)), sspf(bfhi(sp) + bfhi(rp))));
    }
    stage_write(sr, Bs[0], tid);
    __syncthreads();

    // ---- P1: prefetch WT2 k64 -> Bs[1]; GEMM2 chunk0
    f32x4 m0[8] = {}, m1[8] = {};
    stage_load(sr, WT2, 128, 64, tid);
    #pragma unroll
    for (int ks = 0; ks < 2; ++ks) {
        short8 a0 = ldsA(h1, er0, ks * 32 + l4 * 8);
        short8 a1 = ldsA(h1, er1, ks * 32 + l4 * 8);
        #pragma unroll
        for (int f = 0; f < 8; ++f) {
            short8 b = ldsB(Bs[0], f * 16 + l15, ks * 32 + l4 * 8);
            m0[f] = MFMA(a0, b, m0[f]);
            m1[f] = MFMA(a1, b, m1[f]);
        }
    }
    stage_write(sr, Bs[1], tid);
    __syncthreads();

    // ---- P2: prefetch WTe1 -> Bs[0]; GEMM2 chunk1
    stage_load(sr, WTe1, 64, 0, tid);
    #pragma unroll
    for (int ks = 0; ks < 2; ++ks) {
        short8 a0 = ldsA(h1, er0, 64 + ks * 32 + l4 * 8);
        short8 a1 = ldsA(h1, er1, 64 + ks * 32 + l4 * 8);
        #pragma unroll
        for (int f = 0; f < 8; ++f) {
            short8 b = ldsB(Bs[1], f * 16 + l15, ks * 32 + l4 * 8);
            m0[f] = MFMA(a0, b, m0[f]);
            m1[f] = MFMA(a1, b, m1[f]);
        }
    }
    stage_write(sr, Bs[0], tid);
    __syncthreads();

    // pack m_node + bn2 -> bf16 pairs (frees 64 VGPRs)
    unsigned mnp0[16], mnp1[16];
    #pragma unroll
    for (int fp = 0; fp < 4; ++fp) {
        float bl = bn2[fp * 32 + l15], bh = bn2[fp * 32 + 16 + l15];
        #pragma unroll
        for (int r = 0; r < 4; ++r) {
            mnp0[fp * 4 + r] = pk2(m0[2 * fp][r] + bl, m0[2 * fp + 1][r] + bh);
            mnp1[fp * 4 + r] = pk2(m1[2 * fp][r] + bl, m1[2 * fp + 1][r] + bh);
        }
    }

    // ---- P3: prefetch WTe2 k0 -> Bs[1]; GEMM3 rbf @ We1 (A in regs)
    f32x4 c0[8] = {}, c1[8] = {};
    stage_load(sr, WTe2, 128, 0, tid);
    {
        float dv0 = sdv[e0 + er0], dv1 = sdv[e0 + er1];
        #pragma unroll
        for (int ks = 0; ks < 2; ++ks) {
            short8 a0, a1;
            #pragma unroll
            for (int j = 0; j < 8; ++j) {
                int k = ks * 32 + l4 * 8 + j;
                float t0 = dv0 - 0.1f * (float)k;
                float t1 = dv1 - 0.1f * (float)k;
                a0[j] = (k < 50) ? f2bf(expf(-50.0f * t0 * t0)) : (short)0;
                a1[j] = (k < 50) ? f2bf(expf(-50.0f * t1 * t1)) : (short)0;
            }
            #pragma unroll
            for (int f = 0; f < 8; ++f) {
                short8 b = ldsB(Bs[0], f * 16 + l15, ks * 32 + l4 * 8);
                c0[f] = MFMA(a0, b, c0[f]);
                c1[f] = MFMA(a1, b, c1[f]);
            }
        }
    }
    stage_write(sr, Bs[1], tid);
    __syncthreads();

    // ---- P4: prefetch WTe2 k64 -> Bs[0]; filt = ssp(. + be1) -> h1
    stage_load(sr, WTe2, 128, 64, tid);
    #pragma unroll
    for (int fp = 0; fp < 4; ++fp) {
        float bl = be1[fp * 32 + l15], bh = be1[fp * 32 + 16 + l15];
        #pragma unroll
        for (int r = 0; r < 4; ++r) {
            actW(h1, crow + r, fp * 16 + l15,
                 pk2(sspf(c0[2 * fp][r] + bl), sspf(c0[2 * fp + 1][r] + bh)));
            actW(h1, crow + r + 16, fp * 16 + l15,
                 pk2(sspf(c1[2 * fp][r] + bl), sspf(c1[2 * fp + 1][r] + bh)));
        }
    }
    stage_write(sr, Bs[0], tid);
    __syncthreads();

    // ---- P5: GEMM4 both chunks (Bs[1]=k0, Bs[0]=k64); combine; store
    f32x4 g0[8] = {}, g1[8] = {};
    #pragma unroll
    for (int ks = 0; ks < 2; ++ks) {
        short8 a0 = ldsA(h1, er0, ks * 32 + l4 * 8);
        short8 a1 = ldsA(h1, er1, ks * 32 + l4 * 8);
        #pragma unroll
        for (int f = 0; f < 8; ++f) {
            short8 b = ldsB(Bs[1], f * 16 + l15, ks * 32 + l4 * 8);
            g0[f] = MFMA(a0, b, g0[f]);
            g1[f] = MFMA(a1, b, g1[f]);
        }
    }
    #pragma unroll
    for (int ks = 0; ks < 2; ++ks) {
        short8 a0 = ldsA(h1, er0, 64 + ks * 32 + l4 * 8);
        short8 a1 = ldsA(h1, er1, 64 + ks * 32 + l4 * 8);
        #pragma unroll
        for (int f = 0; f < 8; ++f) {
            short8 b = ldsB(Bs[0], f * 16 + l15, ks * 32 + l4 * 8);
            g0[f] = MFMA(a0, b, g0[f]);
            g1[f] = MFMA(a1, b, g1[f]);
        }
    }

    #pragma unroll
    for (int r = 0; r < 4; ++r) {
        float cu0 = scv[e0 + crow + r], cu1 = scv[e0 + crow + 16 + r];
        #pragma unroll
        for (int fp = 0; fp < 4; ++fp) {
            float bl = be2[fp * 32 + l15], bh = be2[fp * 32 + 16 + l15];
            unsigned v0 = mnp0[fp * 4 + r], v1 = mnp1[fp * 4 + r];
            unsigned o0 = pk2(bflo(v0) * ((g0[2 * fp][r] + bl) * cu0),
                              bfhi(v0) * ((g0[2 * fp + 1][r] + bh) * cu0));
            unsigned o1 = pk2(bflo(v1) * ((g1[2 * fp][r] + bl) * cu1),
                              bfhi(v1) * ((g1[2 * fp + 1][r] + bh) * cu1));
            mbufu[(size_t)(e0 + crow + r) * 64 + fp * 16 + l15] = o0;
            mbufu[(size_t)(e0 + crow + 16 + r) * 64 + fp * 16 + l15] = o1;
        }
    }
}

// ---------------- per-layer: segment-sum + state MLP ----------------

__global__ __launch_bounds__(256, 3) void node_mfma_kernel(
    const unsigned* __restrict__ mbufu, const int* __restrict__ segs,
    const unsigned short* __restrict__ WTs1, const float* __restrict__ bs1,
    const unsigned short* __restrict__ WTs2, const float* __restrict__ bs2,
    float* __restrict__ node_state, unsigned short* __restrict__ nsb,
    float* __restrict__ out_l)
{
    __shared__ unsigned short ah[64 * 128];
    __shared__ unsigned short Bs[128 * 64];
    int tid = threadIdx.x;
    int n0 = blockIdx.x * 64;
    {
        int u = tid & 63, ih = tid >> 6;
        for (int i = ih; i < 64; i += 4) {
            int s0 = segs[n0 + i], s1 = segs[n0 + i + 1];
            float aL = 0.0f, aH = 0.0f;
            for (int s = s0; s < s1; ++s) {
                unsigned v = mbufu[(size_t)s * 64 + u];
                aL += bflo(v);
                aH += bfhi(v);
            }
            *(unsigned*)((char*)ah + i * 256 + ((u * 4) ^ ((i & 7) << 4))) = pk2(aL, aH);
        }
    }
    __syncthreads();
    const int wave = tid >> 6, l = tid & 63, l15 = l & 15, l4 = l >> 4;
    const int er = wave * 16 + l15, crow = wave * 16 + l4 * 4;

    f32x4 c1[8] = {};
    #pragma unroll
    for (int c = 0; c < 2; ++c) {
        stage_b64(WTs1, 128, c * 64, Bs, tid);
        __syncthreads();
        #pragma unroll
        for (int ks = 0; ks < 2; ++ks) {
            short8 a = ldsA(ah, er, c * 64 + ks * 32 + l4 * 8);
            #pragma unroll
            for (int f = 0; f < 8; ++f) {
                short8 b = ldsB(Bs, f * 16 + l15, ks * 32 + l4 * 8);
                c1[f] = MFMA(a, b, c1[f]);
            }
        }
        __syncthreads();
    }
    #pragma unroll
    for (int fp = 0; fp < 4; ++fp) {
        float bl = bs1[fp * 32 + l15], bh = bs1[fp * 32 + 16 + l15];
        #pragma unroll
        for (int r = 0; r < 4; ++r)
            actW(ah, crow + r, fp * 16 + l15,
                 pk2(sspf(c1[2 * fp][r] + bl), sspf(c1[2 * fp + 1][r] + bh)));
    }
    __syncthreads();

    f32x4 c2[8] = {};
    #pragma unroll
    for (int c = 0; c < 2; ++c) {
        stage_b64(WTs2, 128, c * 64, Bs, tid);
        __syncthreads();
        #pragma unroll
        for (int ks = 0; ks < 2; ++ks) {
            short8 a = ldsA(ah, er, c * 64 + ks * 32 + l4 * 8);
            #pragma unroll
            for (int f = 0; f < 8; ++f) {
                short8 b = ldsB(Bs, f * 16 + l15, ks * 32 + l4 * 8);
                c2[f] = MFMA(a, b, c2[f]);
            }
        }
        __syncthreads();
    }

    #pragma unroll
    for (int r = 0; r < 4; ++r) {
        int row = n0 + crow + r;
        float vv[8];
        #pragma unroll
        for (int f = 0; f < 8; ++f) {
            int n = f * 16 + l15;
            float v = node_state[(size_t)row * 128 + n] + c2[f][r] + bs2[n];
            node_state[(size_t)row * 128 + n] = v;
            out_l[(size_t)row * 128 + n] = v;
            vv[f] = v;
        }
        #pragma unroll
        for (int fp = 0; fp < 4; ++fp)
            *(unsigned*)&nsb[(size_t)row * 128 + (fp * 16 + l15) * 2] = pk2(vv[2 * fp], vv[2 * fp + 1]);
    }
}

// ---------------- host ----------------

extern "C" void kernel_launch(void* const* d_in, const int* in_sizes, int n_in,
                              void* d_out, int out_size, void* d_ws, size_t ws_size,
                              hipStream_t stream)
{
    const int*   nodes = (const int*)d_in[0];
    const int*   ae    = (const int*)d_in[1];
    const float* aef   = (const float*)d_in[2];
    const float* emb   = (const float*)d_in[5];
    const float* Wn1 = (const float*)d_in[6];  const float* bn1 = (const float*)d_in[7];
    const float* Wn2 = (const float*)d_in[8];  const float* bn2 = (const float*)d_in[9];
    const float* We1 = (const float*)d_in[10]; const float* be1 = (const float*)d_in[11];
    const float* We2 = (const float*)d_in[12]; const float* be2 = (const float*)d_in[13];
    const float* Ws1 = (const float*)d_in[14]; const float* bs1 = (const float*)d_in[15];
    const float* Ws2 = (const float*)d_in[16]; const float* bs2 = (const float*)d_in[17];
    float* out = (float*)d_out;

    char* ws = (char*)d_ws;
    const size_t MB = 1u << 20;
    float*          node_state = (float*)(ws);                    // 8 MB
    unsigned short* nsb        = (unsigned short*)(ws + 8 * MB);  // 4 MB
    unsigned*       mbufu      = (unsigned*)(ws + 12 * MB);       // 64 MB
    int*   ssend  = (int*)(ws + 76 * MB);
    int*   srecv  = (int*)(ws + 77 * MB);
    float* sdv    = (float*)(ws + 78 * MB);
    float* scv    = (float*)(ws + 79 * MB);
    int*   cnt    = (int*)(ws + 80 * MB);
    int*   segs   = (int*)(ws + 80 * MB + 256 * 1024);
    int*   cursor = (int*)(ws + 80 * MB + 512 * 1024);
    unsigned short* WT1  = (unsigned short*)(ws + 81 * MB);                 // 192 KB
    unsigned short* WT2  = (unsigned short*)(ws + 81 * MB + 256 * 1024);
    unsigned short* WTe1 = (unsigned short*)(ws + 81 * MB + 512 * 1024);
    unsigned short* WTe2 = (unsigned short*)(ws + 81 * MB + 768 * 1024);
    unsigned short* WTs1 = (unsigned short*)(ws + 82 * MB);
    unsigned short* WTs2 = (unsigned short*)(ws + 82 * MB + 256 * 1024);
    unsigned* sprojP = (unsigned*)(ws + 83 * MB);                 // 4 MB
    unsigned* rprojP = (unsigned*)(ws + 87 * MB);                 // 4 MB

    wprep_kernel<<<(LNUM * 128 * 256 + 255) / 256, 256, 0, stream>>>(Wn1, WT1, 256, 256, 1);
    wprep_kernel<<<(LNUM * 128 * 128 + 255) / 256, 256, 0, stream>>>(Wn2, WT2, 128, 128, 1);
    wprep_kernel<<<(LNUM * 128 * 64  + 255) / 256, 256, 0, stream>>>(We1, WTe1, 50, 64, 0);
    wprep_kernel<<<(LNUM * 128 * 128 + 255) / 256, 256, 0, stream>>>(We2, WTe2, 128, 128, 1);
    wprep_kernel<<<(LNUM * 128 * 128 + 255) / 256, 256, 0, stream>>>(Ws1, WTs1, 128, 128, 1);
    wprep_kernel<<<(LNUM * 128 * 128 + 255) / 256, 256, 0, stream>>>(Ws2, WTs2, 128, 128, 1);
    init_nodes_kernel<<<NTOT * 128 / 256, 256, 0, stream>>>(nodes, emb, node_state, nsb);
    hipMemsetAsync(cnt, 0, NTOT * sizeof(int), stream);
    count_kernel<<<ETOT / 256, 256, 0, stream>>>(ae, cnt);
    scan_kernel<<<1, 256, 0, stream>>>(cnt, segs, cursor);
    scatter_kernel<<<ETOT / 256, 256, 0, stream>>>(ae, aef, cursor, ssend, srecv, sdv, scv);

    for (int l = 0; l < LNUM; ++l) {
        nodeproj_kernel<<<NTOT / 64, 256, 0, stream>>>(
            nsb, WT1 + (size_t)l * 128 * 256, bn1 + (size_t)l * 128, sprojP, rprojP);
        edge_mfma_kernel<<<ETOT / 128, 256, 0, stream>>>(
            sprojP, rprojP, ssend, srecv, sdv, scv,
            WT2 + (size_t)l * 128 * 128, bn2 + (size_t)l * 128,
            WTe1 + (size_t)l * 128 * 64, be1 + (size_t)l * 128,
            WTe2 + (size_t)l * 128 * 128, be2 + (size_t)l * 128,
            mbufu);
        node_mfma_kernel<<<NTOT / 64, 256, 0, stream>>>(
            mbufu, segs,
            WTs1 + (size_t)l * 128 * 128, bs1 + (size_t)l * 128,
            WTs2 + (size_t)l * 128 * 128, bs2 + (size_t)l * 128,
            node_state, nsb, out + (size_t)l * NTOT * 128);
    }
}

// Round 6
// 403.125 us; speedup vs baseline: 7.6334x; 1.5420x over previous
//
#include <hip/hip_runtime.h>
#include <hip/hip_bf16.h>
#include <math.h>

#define BQ 8
#define NPER 2048
#define EPER 32768
#define NTOT (BQ * NPER)          // 16384
#define ETOT (BQ * EPER)          // 262144
#define HDIM 128
#define LNUM 3

typedef __attribute__((ext_vector_type(8))) short short8;
typedef __attribute__((ext_vector_type(4))) float f32x4;

__device__ __forceinline__ short f2bf(float x) {
    union { float f; unsigned u; } v; v.f = x;
    unsigned r = v.u + 0x7fffu + ((v.u >> 16) & 1u);
    return (short)(r >> 16);
}
// paired f32 -> packed bf16x2 (compiler emits v_cvt_pk_bf16_f32 — m240)
__device__ __forceinline__ unsigned pk2(float lo, float hi) {
    union { __hip_bfloat162 h; unsigned u; } v;
    float2 f; f.x = lo; f.y = hi;
    v.h = __float22bfloat162_rn(f);
    return v.u;
}
__device__ __forceinline__ float bflo(unsigned v) {
    union { unsigned u; float f; } x; x.u = v << 16; return x.f;
}
__device__ __forceinline__ float bfhi(unsigned v) {
    union { unsigned u; float f; } x; x.u = v & 0xffff0000u; return x.f;
}
__device__ __forceinline__ float sspf(float x) {
    return 0.6931471805599453f * (log2f(1.0f + exp2f(x * 1.4426950408889634f)) - 1.0f);
}

// ---- LDS helpers (XOR-swizzled; act rows 256B, B rows 128B) ----
__device__ __forceinline__ short8 ldsA(const unsigned short* t, int row, int pos) {
    return *(const short8*)((const char*)t + row * 256 + ((pos * 2) ^ ((row & 7) << 4)));
}
__device__ __forceinline__ short8 ldsB(const unsigned short* t, int n, int pos) {
    return *(const short8*)((const char*)t + n * 128 + ((pos * 2) ^ ((n & 7) << 4)));
}
__device__ __forceinline__ void actW(unsigned short* t, int row, int dw, unsigned v) {
    *(unsigned*)((char*)t + row * 256 + ((dw * 4) ^ ((row & 7) << 4))) = v;
}

// ---- T14 async-STAGE split: load-early (regs, LINEAR source), write-late (swizzled LDS) ----
struct StageReg { uint4 v[4]; };
__device__ __forceinline__ void stage_load(StageReg& s, const unsigned short* __restrict__ src,
                                           int strideK, int kbase, int tid) {
    #pragma unroll
    for (int it = 0; it < 4; ++it) {
        int u = it * 256 + tid;          // 16B unit
        int n = u >> 3, kd8 = u & 7;     // LINEAR source
        s.v[it] = *(const uint4*)&src[(size_t)n * strideK + kbase + kd8 * 8];
    }
}
__device__ __forceinline__ void stage_write(const StageReg& s, unsigned short* Bs, int tid) {
    #pragma unroll
    for (int it = 0; it < 4; ++it) {
        int u = it * 256 + tid;
        int n = u >> 3;
        *(uint4*)((char*)Bs + ((u * 16) ^ ((n & 7) << 4))) = s.v[it];
    }
}
// legacy 8B-unit stager (node kernel)
__device__ __forceinline__ void stage_b64(const unsigned short* __restrict__ src, int strideK, int kbase,
                                          unsigned short* __restrict__ Bs, int tid) {
    #pragma unroll
    for (int it = 0; it < 8; ++it) {
        int i = it * 256 + tid;
        int n = i >> 4, kd2 = i & 15;
        uint2 v = *(const uint2*)&src[(size_t)n * strideK + kbase + kd2 * 4];
        *(uint2*)((char*)Bs + n * 128 + ((kd2 * 8) ^ ((n & 7) << 4))) = v;
    }
}

#define MFMA(A, B, C) __builtin_amdgcn_mfma_f32_16x16x32_bf16(A, B, C, 0, 0, 0)

// ---------------- once-per-launch prep ----------------

__global__ __launch_bounds__(256) void wprep_kernel(
    const float* __restrict__ W, unsigned short* __restrict__ WT,
    int K, int KP, int doperm)
{
    int idx = blockIdx.x * 256 + threadIdx.x;
    int total = LNUM * 128 * KP;
    if (idx >= total) return;
    int l = idx / (128 * KP);
    int rem = idx - l * (128 * KP);
    int n = rem / KP;
    int p = rem - n * KP;
    int k;
    if (doperm) {
        int half = p >> 7, pp = p & 127;
        k = (half << 7) | ((pp >> 5) << 5) | ((pp & 1) << 4) | ((pp & 31) >> 1);
    } else k = p;
    float v = (k < K) ? W[((size_t)l * K + k) * 128 + n] : 0.0f;
    WT[idx] = (unsigned short)f2bf(v);
}

__global__ __launch_bounds__(256) void init_nodes_kernel(
    const int* __restrict__ nodes, const float* __restrict__ emb,
    float* __restrict__ node_state, unsigned short* __restrict__ nsb)
{
    int idx = blockIdx.x * 256 + threadIdx.x;
    int n = idx >> 7, p = idx & 127;
    int j = ((p >> 5) << 5) | ((p & 1) << 4) | ((p & 31) >> 1);
    float v = emb[(size_t)nodes[n] * 128 + j];
    nsb[idx] = (unsigned short)f2bf(v);
    node_state[(n << 7) + j] = v;
}

__global__ __launch_bounds__(256) void count_kernel(const int* __restrict__ ae, int* __restrict__ cnt)
{
    int g = blockIdx.x * 256 + threadIdx.x;
    int b = g >> 15;
    atomicAdd(&cnt[ae[2 * g + 1] + b * NPER], 1);
}

__global__ __launch_bounds__(256) void scan_kernel(
    const int* __restrict__ cnt, int* __restrict__ segs, int* __restrict__ cursor)
{
    __shared__ int part[256];
    int t = threadIdx.x;
    int base = t * 64;
    int s = 0;
    for (int i = 0; i < 64; ++i) s += cnt[base + i];
    part[t] = s;
    __syncthreads();
    for (int ofs = 1; ofs < 256; ofs <<= 1) {
        int v = part[t];
        int add = (t >= ofs) ? part[t - ofs] : 0;
        __syncthreads();
        part[t] = v + add;
        __syncthreads();
    }
    int run = part[t] - s;
    for (int i = 0; i < 64; ++i) {
        segs[base + i] = run;
        cursor[base + i] = run;
        run += cnt[base + i];
    }
    if (t == 255) segs[NTOT] = run;
}

__global__ __launch_bounds__(256) void scatter_kernel(
    const int* __restrict__ ae, const float* __restrict__ aef, int* __restrict__ cursor,
    int* __restrict__ ssend, int* __restrict__ srecv,
    float* __restrict__ sdv, float* __restrict__ scv)
{
    int g = blockIdx.x * 256 + threadIdx.x;
    int b = g >> 15;
    int sn = ae[2 * g] + b * NPER, rv = ae[2 * g + 1] + b * NPER;
    int pos = atomicAdd(&cursor[rv], 1);
    ssend[pos] = sn; srecv[pos] = rv;
    float dd = aef[g];
    sdv[pos] = dd;
    scv[pos] = 1.0f - 1.0f / (1.0f + expf(-5.0f * (dd - 3.5f)));
}

// ---------------- per-layer: node projections (replaces edge GEMM1) ----------------

__global__ __launch_bounds__(256, 3) void nodeproj_kernel(
    const unsigned short* __restrict__ nsb,
    const unsigned short* __restrict__ WT1, const float* __restrict__ bn1,
    unsigned* __restrict__ sprojP, unsigned* __restrict__ rprojP)
{
    __shared__ unsigned short Bs[2][64 * 128];
    const int tid = threadIdx.x;
    const int n0 = blockIdx.x * 64;
    const int wv = tid >> 6, l = tid & 63, l15 = l & 15, l4 = l >> 4;
    const int er = wv * 16 + l15, crow = wv * 16 + l4 * 4;

    short8 a[4];
    #pragma unroll
    for (int ks = 0; ks < 4; ++ks)
        a[ks] = *(const short8*)&nsb[(size_t)(n0 + er) * 128 + ks * 32 + l4 * 8];

    StageReg sr;
    stage_load(sr, WT1, 256, 0, tid);
    stage_write(sr, Bs[0], tid);
    __syncthreads();

    f32x4 cs[8] = {}, cr[8] = {};
    stage_load(sr, WT1, 256, 64, tid);
    #pragma unroll
    for (int ks = 0; ks < 2; ++ks)
        #pragma unroll
        for (int f = 0; f < 8; ++f)
            cs[f] = MFMA(a[ks], ldsB(Bs[0], f * 16 + l15, ks * 32 + l4 * 8), cs[f]);
    stage_write(sr, Bs[1], tid);
    __syncthreads();
    stage_load(sr, WT1, 256, 128, tid);
    #pragma unroll
    for (int ks = 0; ks < 2; ++ks)
        #pragma unroll
        for (int f = 0; f < 8; ++f)
            cs[f] = MFMA(a[2 + ks], ldsB(Bs[1], f * 16 + l15, ks * 32 + l4 * 8), cs[f]);
    stage_write(sr, Bs[0], tid);
    __syncthreads();
    stage_load(sr, WT1, 256, 192, tid);
    #pragma unroll
    for (int ks = 0; ks < 2; ++ks)
        #pragma unroll
        for (int f = 0; f < 8; ++f)
            cr[f] = MFMA(a[ks], ldsB(Bs[0], f * 16 + l15, ks * 32 + l4 * 8), cr[f]);
    stage_write(sr, Bs[1], tid);
    __syncthreads();
    #pragma unroll
    for (int ks = 0; ks < 2; ++ks)
        #pragma unroll
        for (int f = 0; f < 8; ++f)
            cr[f] = MFMA(a[2 + ks], ldsB(Bs[1], f * 16 + l15, ks * 32 + l4 * 8), cr[f]);

    #pragma unroll
    for (int fp = 0; fp < 4; ++fp) {
        float bl = bn1[fp * 32 + l15], bh = bn1[fp * 32 + 16 + l15];
        #pragma unroll
        for (int r = 0; r < 4; ++r) {
            size_t o = (size_t)(n0 + crow + r) * 64 + fp * 16 + l15;
            sprojP[o] = pk2(cs[2 * fp][r] + bl, cs[2 * fp + 1][r] + bh);
            rprojP[o] = pk2(cr[2 * fp][r], cr[2 * fp + 1][r]);
        }
    }
}

// ---------------- per-layer: edge messages ----------------

__global__ __launch_bounds__(256, 2) void edge_mfma_kernel(
    const unsigned* __restrict__ sprojP, const unsigned* __restrict__ rprojP,
    const int* __restrict__ ssend, const int* __restrict__ srecv,
    const float* __restrict__ sdv, const float* __restrict__ scv,
    const unsigned short* __restrict__ WT2, const float* __restrict__ bn2,
    const unsigned short* __restrict__ WTe1, const float* __restrict__ be1,
    const unsigned short* __restrict__ WTe2, const float* __restrict__ be2,
    unsigned* __restrict__ mbufu)
{
    __shared__ unsigned short h1[128 * 128];   // 32 KB act tile (swizzled 256B rows)
    __shared__ unsigned short Bs[2][64 * 128]; // 2 x 16 KB B panels
    const int tid = threadIdx.x;
    const int e0 = blockIdx.x * 128;
    const int wv = tid >> 6, l = tid & 63, l15 = l & 15, l4 = l >> 4;
    const int er0 = wv * 32 + l15, er1 = er0 + 16;
    const int crow = wv * 32 + l4 * 4;

    StageReg sr;
    // ---- P0: prefetch WT2 k0 -> Bs[0]; h1 = ssp(sproj[s] + rproj[r])
    stage_load(sr, WT2, 128, 0, tid);
    #pragma unroll 4
    for (int it = 0; it < 32; ++it) {
        int e = wv * 32 + it;
        int sn = ssend[e0 + e], rn = srecv[e0 + e];
        unsigned sp = sprojP[(size_t)sn * 64 + l];
        unsigned rp = rprojP[(size_t)rn * 64 + l];
        actW(h1, e, l, pk2(sspf(bflo(sp) + bflo(rp)), sspf(bfhi(sp) + bfhi(rp))));
    }
    stage_write(sr, Bs[0], tid);
    __syncthreads();

    // ---- P1: prefetch WT2 k64 -> Bs[1]; GEMM2 chunk0
    f32x4 m0[8] = {}, m1[8] = {};
    stage_load(sr, WT2, 128, 64, tid);
    #pragma unroll
    for (int ks = 0; ks < 2; ++ks) {
        short8 a0 = ldsA(h1, er0, ks * 32 + l4 * 8);
        short8 a1 = ldsA(h1, er1, ks * 32 + l4 * 8);
        #pragma unroll
        for (int f = 0; f < 8; ++f) {
            short8 b = ldsB(Bs[0], f * 16 + l15, ks * 32 + l4 * 8);
            m0[f] = MFMA(a0, b, m0[f]);
            m1[f] = MFMA(a1, b, m1[f]);
        }
    }
    stage_write(sr, Bs[1], tid);
    __syncthreads();

    // ---- P2: prefetch WTe1 -> Bs[0]; GEMM2 chunk1
    stage_load(sr, WTe1, 64, 0, tid);
    #pragma unroll
    for (int ks = 0; ks < 2; ++ks) {
        short8 a0 = ldsA(h1, er0, 64 + ks * 32 + l4 * 8);
        short8 a1 = ldsA(h1, er1, 64 + ks * 32 + l4 * 8);
        #pragma unroll
        for (int f = 0; f < 8; ++f) {
            short8 b = ldsB(Bs[1], f * 16 + l15, ks * 32 + l4 * 8);
            m0[f] = MFMA(a0, b, m0[f]);
            m1[f] = MFMA(a1, b, m1[f]);
        }
    }
    stage_write(sr, Bs[0], tid);
    __syncthreads();

    // pack m_node + bn2 -> bf16 pairs
    unsigned mnp0[16], mnp1[16];
    #pragma unroll
    for (int fp = 0; fp < 4; ++fp) {
        float bl = bn2[fp * 32 + l15], bh = bn2[fp * 32 + 16 + l15];
        #pragma unroll
        for (int r = 0; r < 4; ++r) {
            mnp0[fp * 4 + r] = pk2(m0[2 * fp][r] + bl, m0[2 * fp + 1][r] + bh);
            mnp1[fp * 4 + r] = pk2(m1[2 * fp][r] + bl, m1[2 * fp + 1][r] + bh);
        }
    }

    // ---- P3: prefetch WTe2 k0 -> Bs[1]; GEMM3 rbf @ We1 (A in regs)
    f32x4 c0[8] = {}, c1[8] = {};
    stage_load(sr, WTe2, 128, 0, tid);
    {
        float dv0 = sdv[e0 + er0], dv1 = sdv[e0 + er1];
        #pragma unroll
        for (int ks = 0; ks < 2; ++ks) {
            short8 a0, a1;
            #pragma unroll
            for (int j = 0; j < 8; ++j) {
                int k = ks * 32 + l4 * 8 + j;
                float t0 = dv0 - 0.1f * (float)k;
                float t1 = dv1 - 0.1f * (float)k;
                a0[j] = (k < 50) ? f2bf(expf(-50.0f * t0 * t0)) : (short)0;
                a1[j] = (k < 50) ? f2bf(expf(-50.0f * t1 * t1)) : (short)0;
            }
            #pragma unroll
            for (int f = 0; f < 8; ++f) {
                short8 b = ldsB(Bs[0], f * 16 + l15, ks * 32 + l4 * 8);
                c0[f] = MFMA(a0, b, c0[f]);
                c1[f] = MFMA(a1, b, c1[f]);
            }
        }
    }
    stage_write(sr, Bs[1], tid);
    __syncthreads();

    // ---- P4: prefetch WTe2 k64 -> Bs[0]; filt = ssp(. + be1) -> h1
    stage_load(sr, WTe2, 128, 64, tid);
    #pragma unroll
    for (int fp = 0; fp < 4; ++fp) {
        float bl = be1[fp * 32 + l15], bh = be1[fp * 32 + 16 + l15];
        #pragma unroll
        for (int r = 0; r < 4; ++r) {
            actW(h1, crow + r, fp * 16 + l15,
                 pk2(sspf(c0[2 * fp][r] + bl), sspf(c0[2 * fp + 1][r] + bh)));
            actW(h1, crow + r + 16, fp * 16 + l15,
                 pk2(sspf(c1[2 * fp][r] + bl), sspf(c1[2 * fp + 1][r] + bh)));
        }
    }
    stage_write(sr, Bs[0], tid);
    __syncthreads();

    // ---- P5: GEMM4 both chunks (Bs[1]=k0, Bs[0]=k64); combine; store
    f32x4 g0[8] = {}, g1[8] = {};
    #pragma unroll
    for (int ks = 0; ks < 2; ++ks) {
        short8 a0 = ldsA(h1, er0, ks * 32 + l4 * 8);
        short8 a1 = ldsA(h1, er1, ks * 32 + l4 * 8);
        #pragma unroll
        for (int f = 0; f < 8; ++f) {
            short8 b = ldsB(Bs[1], f * 16 + l15, ks * 32 + l4 * 8);
            g0[f] = MFMA(a0, b, g0[f]);
            g1[f] = MFMA(a1, b, g1[f]);
        }
    }
    #pragma unroll
    for (int ks = 0; ks < 2; ++ks) {
        short8 a0 = ldsA(h1, er0, 64 + ks * 32 + l4 * 8);
        short8 a1 = ldsA(h1, er1, 64 + ks * 32 + l4 * 8);
        #pragma unroll
        for (int f = 0; f < 8; ++f) {
            short8 b = ldsB(Bs[0], f * 16 + l15, ks * 32 + l4 * 8);
            g0[f] = MFMA(a0, b, g0[f]);
            g1[f] = MFMA(a1, b, g1[f]);
        }
    }

    #pragma unroll
    for (int r = 0; r < 4; ++r) {
        float cu0 = scv[e0 + crow + r], cu1 = scv[e0 + crow + 16 + r];
        #pragma unroll
        for (int fp = 0; fp < 4; ++fp) {
            float bl = be2[fp * 32 + l15], bh = be2[fp * 32 + 16 + l15];
            unsigned v0 = mnp0[fp * 4 + r], v1 = mnp1[fp * 4 + r];
            unsigned o0 = pk2(bflo(v0) * ((g0[2 * fp][r] + bl) * cu0),
                              bfhi(v0) * ((g0[2 * fp + 1][r] + bh) * cu0));
            unsigned o1 = pk2(bflo(v1) * ((g1[2 * fp][r] + bl) * cu1),
                              bfhi(v1) * ((g1[2 * fp + 1][r] + bh) * cu1));
            mbufu[(size_t)(e0 + crow + r) * 64 + fp * 16 + l15] = o0;
            mbufu[(size_t)(e0 + crow + 16 + r) * 64 + fp * 16 + l15] = o1;
        }
    }
}

// ---------------- per-layer: parallel segment-sum (1 wave per node row) ----------------

__global__ __launch_bounds__(256, 8) void segsum_kernel(
    const unsigned* __restrict__ mbufu, const int* __restrict__ segs,
    unsigned* __restrict__ msumP)
{
    const int wv = threadIdx.x >> 6, u = threadIdx.x & 63;
    const int row = blockIdx.x * 4 + wv;
    const int s0 = segs[row], s1 = segs[row + 1];
    float aL0 = 0, aH0 = 0, aL1 = 0, aH1 = 0, aL2 = 0, aH2 = 0, aL3 = 0, aH3 = 0;
    int s = s0;
    for (; s + 4 <= s1; s += 4) {
        unsigned v0 = mbufu[(size_t)(s + 0) * 64 + u];
        unsigned v1 = mbufu[(size_t)(s + 1) * 64 + u];
        unsigned v2 = mbufu[(size_t)(s + 2) * 64 + u];
        unsigned v3 = mbufu[(size_t)(s + 3) * 64 + u];
        aL0 += bflo(v0); aH0 += bfhi(v0);
        aL1 += bflo(v1); aH1 += bfhi(v1);
        aL2 += bflo(v2); aH2 += bfhi(v2);
        aL3 += bflo(v3); aH3 += bfhi(v3);
    }
    for (; s < s1; ++s) {
        unsigned v = mbufu[(size_t)s * 64 + u];
        aL0 += bflo(v); aH0 += bfhi(v);
    }
    msumP[(size_t)row * 64 + u] = pk2((aL0 + aL1) + (aL2 + aL3), (aH0 + aH1) + (aH2 + aH3));
}

// ---------------- per-layer: state MLP ----------------

__global__ __launch_bounds__(256, 3) void node_mfma_kernel(
    const unsigned* __restrict__ msumP,
    const unsigned short* __restrict__ WTs1, const float* __restrict__ bs1,
    const unsigned short* __restrict__ WTs2, const float* __restrict__ bs2,
    float* __restrict__ node_state, unsigned short* __restrict__ nsb,
    float* __restrict__ out_l)
{
    __shared__ unsigned short ah[64 * 128];
    __shared__ unsigned short Bs[128 * 64];
    int tid = threadIdx.x;
    int n0 = blockIdx.x * 64;
    #pragma unroll
    for (int it = 0; it < 16; ++it) {
        int idx = it * 256 + tid;                 // 64 rows x 64 dwords
        int i = idx >> 6, u = idx & 63;
        unsigned v = msumP[(size_t)(n0 + i) * 64 + u];
        *(unsigned*)((char*)ah + i * 256 + ((u * 4) ^ ((i & 7) << 4))) = v;
    }
    __syncthreads();
    const int wave = tid >> 6, l = tid & 63, l15 = l & 15, l4 = l >> 4;
    const int er = wave * 16 + l15, crow = wave * 16 + l4 * 4;

    f32x4 c1[8] = {};
    #pragma unroll
    for (int c = 0; c < 2; ++c) {
        stage_b64(WTs1, 128, c * 64, Bs, tid);
        __syncthreads();
        #pragma unroll
        for (int ks = 0; ks < 2; ++ks) {
            short8 a = ldsA(ah, er, c * 64 + ks * 32 + l4 * 8);
            #pragma unroll
            for (int f = 0; f < 8; ++f) {
                short8 b = ldsB(Bs, f * 16 + l15, ks * 32 + l4 * 8);
                c1[f] = MFMA(a, b, c1[f]);
            }
        }
        __syncthreads();
    }
    #pragma unroll
    for (int fp = 0; fp < 4; ++fp) {
        float bl = bs1[fp * 32 + l15], bh = bs1[fp * 32 + 16 + l15];
        #pragma unroll
        for (int r = 0; r < 4; ++r)
            actW(ah, crow + r, fp * 16 + l15,
                 pk2(sspf(c1[2 * fp][r] + bl), sspf(c1[2 * fp + 1][r] + bh)));
    }
    __syncthreads();

    f32x4 c2[8] = {};
    #pragma unroll
    for (int c = 0; c < 2; ++c) {
        stage_b64(WTs2, 128, c * 64, Bs, tid);
        __syncthreads();
        #pragma unroll
        for (int ks = 0; ks < 2; ++ks) {
            short8 a = ldsA(ah, er, c * 64 + ks * 32 + l4 * 8);
            #pragma unroll
            for (int f = 0; f < 8; ++f) {
                short8 b = ldsB(Bs, f * 16 + l15, ks * 32 + l4 * 8);
                c2[f] = MFMA(a, b, c2[f]);
            }
        }
        __syncthreads();
    }

    #pragma unroll
    for (int r = 0; r < 4; ++r) {
        int row = n0 + crow + r;
        float vv[8];
        #pragma unroll
        for (int f = 0; f < 8; ++f) {
            int n = f * 16 + l15;
            float v = node_state[(size_t)row * 128 + n] + c2[f][r] + bs2[n];
            node_state[(size_t)row * 128 + n] = v;
            out_l[(size_t)row * 128 + n] = v;
            vv[f] = v;
        }
        #pragma unroll
        for (int fp = 0; fp < 4; ++fp)
            *(unsigned*)&nsb[(size_t)row * 128 + (fp * 16 + l15) * 2] = pk2(vv[2 * fp], vv[2 * fp + 1]);
    }
}

// ---------------- host ----------------

extern "C" void kernel_launch(void* const* d_in, const int* in_sizes, int n_in,
                              void* d_out, int out_size, void* d_ws, size_t ws_size,
                              hipStream_t stream)
{
    const int*   nodes = (const int*)d_in[0];
    const int*   ae    = (const int*)d_in[1];
    const float* aef   = (const float*)d_in[2];
    const float* emb   = (const float*)d_in[5];
    const float* Wn1 = (const float*)d_in[6];  const float* bn1 = (const float*)d_in[7];
    const float* Wn2 = (const float*)d_in[8];  const float* bn2 = (const float*)d_in[9];
    const float* We1 = (const float*)d_in[10]; const float* be1 = (const float*)d_in[11];
    const float* We2 = (const float*)d_in[12]; const float* be2 = (const float*)d_in[13];
    const float* Ws1 = (const float*)d_in[14]; const float* bs1 = (const float*)d_in[15];
    const float* Ws2 = (const float*)d_in[16]; const float* bs2 = (const float*)d_in[17];
    float* out = (float*)d_out;

    char* ws = (char*)d_ws;
    const size_t MB = 1u << 20;
    float*          node_state = (float*)(ws);                    // 8 MB
    unsigned short* nsb        = (unsigned short*)(ws + 8 * MB);  // 4 MB
    unsigned*       mbufu      = (unsigned*)(ws + 12 * MB);       // 64 MB
    int*   ssend  = (int*)(ws + 76 * MB);
    int*   srecv  = (int*)(ws + 77 * MB);
    float* sdv    = (float*)(ws + 78 * MB);
    float* scv    = (float*)(ws + 79 * MB);
    int*   cnt    = (int*)(ws + 80 * MB);
    int*   segs   = (int*)(ws + 80 * MB + 256 * 1024);
    int*   cursor = (int*)(ws + 80 * MB + 512 * 1024);
    unsigned short* WT1  = (unsigned short*)(ws + 81 * MB);
    unsigned short* WT2  = (unsigned short*)(ws + 81 * MB + 256 * 1024);
    unsigned short* WTe1 = (unsigned short*)(ws + 81 * MB + 512 * 1024);
    unsigned short* WTe2 = (unsigned short*)(ws + 81 * MB + 768 * 1024);
    unsigned short* WTs1 = (unsigned short*)(ws + 82 * MB);
    unsigned short* WTs2 = (unsigned short*)(ws + 82 * MB + 256 * 1024);
    unsigned* sprojP = (unsigned*)(ws + 83 * MB);                 // 4 MB
    unsigned* rprojP = (unsigned*)(ws + 87 * MB);                 // 4 MB
    unsigned* msumP  = (unsigned*)(ws + 91 * MB);                 // 4 MB

    wprep_kernel<<<(LNUM * 128 * 256 + 255) / 256, 256, 0, stream>>>(Wn1, WT1, 256, 256, 1);
    wprep_kernel<<<(LNUM * 128 * 128 + 255) / 256, 256, 0, stream>>>(Wn2, WT2, 128, 128, 1);
    wprep_kernel<<<(LNUM * 128 * 64  + 255) / 256, 256, 0, stream>>>(We1, WTe1, 50, 64, 0);
    wprep_kernel<<<(LNUM * 128 * 128 + 255) / 256, 256, 0, stream>>>(We2, WTe2, 128, 128, 1);
    wprep_kernel<<<(LNUM * 128 * 128 + 255) / 256, 256, 0, stream>>>(Ws1, WTs1, 128, 128, 1);
    wprep_kernel<<<(LNUM * 128 * 128 + 255) / 256, 256, 0, stream>>>(Ws2, WTs2, 128, 128, 1);
    init_nodes_kernel<<<NTOT * 128 / 256, 256, 0, stream>>>(nodes, emb, node_state, nsb);
    hipMemsetAsync(cnt, 0, NTOT * sizeof(int), stream);
    count_kernel<<<ETOT / 256, 256, 0, stream>>>(ae, cnt);
    scan_kernel<<<1, 256, 0, stream>>>(cnt, segs, cursor);
    scatter_kernel<<<ETOT / 256, 256, 0, stream>>>(ae, aef, cursor, ssend, srecv, sdv, scv);

    for (int l = 0; l < LNUM; ++l) {
        nodeproj_kernel<<<NTOT / 64, 256, 0, stream>>>(
            nsb, WT1 + (size_t)l * 128 * 256, bn1 + (size_t)l * 128, sprojP, rprojP);
        edge_mfma_kernel<<<ETOT / 128, 256, 0, stream>>>(
            sprojP, rprojP, ssend, srecv, sdv, scv,
            WT2 + (size_t)l * 128 * 128, bn2 + (size_t)l * 128,
            WTe1 + (size_t)l * 128 * 64, be1 + (size_t)l * 128,
            WTe2 + (size_t)l * 128 * 128, be2 + (size_t)l * 128,
            mbufu);
        segsum_kernel<<<NTOT / 4, 256, 0, stream>>>(mbufu, segs, msumP);
        node_mfma_kernel<<<NTOT / 64, 256, 0, stream>>>(
            msumP,
            WTs1 + (size_t)l * 128 * 128, bs1 + (size_t)l * 128,
            WTs2 + (size_t)l * 128 * 128, bs2 + (size_t)l * 128,
            node_state, nsb, out + (size_t)l * NTOT * 128);
    }
}

// Round 7
// 355.024 us; speedup vs baseline: 8.6676x; 1.1355x over previous
//
#include <hip/hip_runtime.h>
#include <hip/hip_bf16.h>
#include <math.h>

#define BQ 8
#define NPER 2048
#define EPER 32768
#define NTOT (BQ * NPER)          // 16384
#define ETOT (BQ * EPER)          // 262144
#define HDIM 128
#define LNUM 3

typedef __attribute__((ext_vector_type(8))) short short8;
typedef __attribute__((ext_vector_type(4))) float f32x4;

__device__ __forceinline__ short f2bf(float x) {
    union { float f; unsigned u; } v; v.f = x;
    unsigned r = v.u + 0x7fffu + ((v.u >> 16) & 1u);
    return (short)(r >> 16);
}
// paired f32 -> packed bf16x2 (compiler emits v_cvt_pk_bf16_f32 — m240)
__device__ __forceinline__ unsigned pk2(float lo, float hi) {
    union { __hip_bfloat162 h; unsigned u; } v;
    float2 f; f.x = lo; f.y = hi;
    v.h = __float22bfloat162_rn(f);
    return v.u;
}
__device__ __forceinline__ float bflo(unsigned v) {
    union { unsigned u; float f; } x; x.u = v << 16; return x.f;
}
__device__ __forceinline__ float bfhi(unsigned v) {
    union { unsigned u; float f; } x; x.u = v & 0xffff0000u; return x.f;
}
// softplus(x)-ln2 via HW transcendentals (v_exp_f32 / v_log_f32, ~1ulp)
__device__ __forceinline__ float sspf(float x) {
    float e = __builtin_amdgcn_exp2f(x * 1.4426950408889634f);
    return 0.6931471805599453f * (__builtin_amdgcn_logf(1.0f + e) - 1.0f);
}
#define EXP2H(x) __builtin_amdgcn_exp2f(x)

// ---- LDS helpers (XOR-swizzled; act rows 256B, B rows 128B) ----
__device__ __forceinline__ short8 ldsA(const unsigned short* t, int row, int pos) {
    return *(const short8*)((const char*)t + row * 256 + ((pos * 2) ^ ((row & 7) << 4)));
}
__device__ __forceinline__ short8 ldsB(const unsigned short* t, int n, int pos) {
    return *(const short8*)((const char*)t + n * 128 + ((pos * 2) ^ ((n & 7) << 4)));
}
__device__ __forceinline__ void actW(unsigned short* t, int row, int dw, unsigned v) {
    *(unsigned*)((char*)t + row * 256 + ((dw * 4) ^ ((row & 7) << 4))) = v;
}

// ---- T14 async-STAGE split: load-early (regs, LINEAR source), write-late (swizzled LDS) ----
struct StageReg { uint4 v[4]; };
__device__ __forceinline__ void stage_load(StageReg& s, const unsigned short* __restrict__ src,
                                           int strideK, int kbase, int tid) {
    #pragma unroll
    for (int it = 0; it < 4; ++it) {
        int u = it * 256 + tid;          // 16B unit
        int n = u >> 3, kd8 = u & 7;     // LINEAR source
        s.v[it] = *(const uint4*)&src[(size_t)n * strideK + kbase + kd8 * 8];
    }
}
__device__ __forceinline__ void stage_write(const StageReg& s, unsigned short* Bs, int tid) {
    #pragma unroll
    for (int it = 0; it < 4; ++it) {
        int u = it * 256 + tid;
        int n = u >> 3;
        *(uint4*)((char*)Bs + ((u * 16) ^ ((n & 7) << 4))) = s.v[it];
    }
}
// legacy 8B-unit stager (node kernel)
__device__ __forceinline__ void stage_b64(const unsigned short* __restrict__ src, int strideK, int kbase,
                                          unsigned short* __restrict__ Bs, int tid) {
    #pragma unroll
    for (int it = 0; it < 8; ++it) {
        int i = it * 256 + tid;
        int n = i >> 4, kd2 = i & 15;
        uint2 v = *(const uint2*)&src[(size_t)n * strideK + kbase + kd2 * 4];
        *(uint2*)((char*)Bs + n * 128 + ((kd2 * 8) ^ ((n & 7) << 4))) = v;
    }
}

#define MFMA(A, B, C) __builtin_amdgcn_mfma_f32_16x16x32_bf16(A, B, C, 0, 0, 0)

// ---------------- once-per-launch prep ----------------

__global__ __launch_bounds__(256) void wprep_kernel(
    const float* __restrict__ W, unsigned short* __restrict__ WT,
    int K, int KP, int doperm)
{
    int idx = blockIdx.x * 256 + threadIdx.x;
    int total = LNUM * 128 * KP;
    if (idx >= total) return;
    int l = idx / (128 * KP);
    int rem = idx - l * (128 * KP);
    int n = rem / KP;
    int p = rem - n * KP;
    int k;
    if (doperm) {
        int half = p >> 7, pp = p & 127;
        k = (half << 7) | ((pp >> 5) << 5) | ((pp & 1) << 4) | ((pp & 31) >> 1);
    } else k = p;
    float v = (k < K) ? W[((size_t)l * K + k) * 128 + n] : 0.0f;
    WT[idx] = (unsigned short)f2bf(v);
}

__global__ __launch_bounds__(256) void init_nodes_kernel(
    const int* __restrict__ nodes, const float* __restrict__ emb,
    float* __restrict__ node_state, unsigned short* __restrict__ nsb)
{
    int idx = blockIdx.x * 256 + threadIdx.x;
    int n = idx >> 7, p = idx & 127;
    int j = ((p >> 5) << 5) | ((p & 1) << 4) | ((p & 31) >> 1);
    float v = emb[(size_t)nodes[n] * 128 + j];
    nsb[idx] = (unsigned short)f2bf(v);
    node_state[(n << 7) + j] = v;
}

__global__ __launch_bounds__(256) void count_kernel(const int* __restrict__ ae, int* __restrict__ cnt)
{
    int g = blockIdx.x * 256 + threadIdx.x;
    int b = g >> 15;
    atomicAdd(&cnt[ae[2 * g + 1] + b * NPER], 1);
}

__global__ __launch_bounds__(256) void scan_kernel(
    const int* __restrict__ cnt, int* __restrict__ segs, int* __restrict__ cursor)
{
    __shared__ int part[256];
    int t = threadIdx.x;
    int base = t * 64;
    int s = 0;
    for (int i = 0; i < 64; ++i) s += cnt[base + i];
    part[t] = s;
    __syncthreads();
    for (int ofs = 1; ofs < 256; ofs <<= 1) {
        int v = part[t];
        int add = (t >= ofs) ? part[t - ofs] : 0;
        __syncthreads();
        part[t] = v + add;
        __syncthreads();
    }
    int run = part[t] - s;
    for (int i = 0; i < 64; ++i) {
        segs[base + i] = run;
        cursor[base + i] = run;
        run += cnt[base + i];
    }
    if (t == 255) segs[NTOT] = run;
}

__global__ __launch_bounds__(256) void scatter_kernel(
    const int* __restrict__ ae, const float* __restrict__ aef, int* __restrict__ cursor,
    int* __restrict__ ssend, int* __restrict__ srecv,
    float* __restrict__ sdv, float* __restrict__ scv)
{
    int g = blockIdx.x * 256 + threadIdx.x;
    int b = g >> 15;
    int sn = ae[2 * g] + b * NPER, rv = ae[2 * g + 1] + b * NPER;
    int pos = atomicAdd(&cursor[rv], 1);
    ssend[pos] = sn; srecv[pos] = rv;
    float dd = aef[g];
    sdv[pos] = dd;
    // 1 - sigmoid(5(d-3.5)) = 1/(1+e^{5(d-3.5)})
    scv[pos] = 1.0f / (1.0f + EXP2H(7.2134752044448170f * (dd - 3.5f)));
}

// ---------------- per-layer: node projections (replaces edge GEMM1) ----------------

__global__ __launch_bounds__(256, 3) void nodeproj_kernel(
    const unsigned short* __restrict__ nsb,
    const unsigned short* __restrict__ WT1, const float* __restrict__ bn1,
    unsigned* __restrict__ sprojP, unsigned* __restrict__ rprojP)
{
    __shared__ unsigned short Bs[2][64 * 128];
    const int tid = threadIdx.x;
    const int n0 = blockIdx.x * 64;
    const int wv = tid >> 6, l = tid & 63, l15 = l & 15, l4 = l >> 4;
    const int er = wv * 16 + l15, crow = wv * 16 + l4 * 4;

    short8 a[4];
    #pragma unroll
    for (int ks = 0; ks < 4; ++ks)
        a[ks] = *(const short8*)&nsb[(size_t)(n0 + er) * 128 + ks * 32 + l4 * 8];

    StageReg sr;
    stage_load(sr, WT1, 256, 0, tid);
    stage_write(sr, Bs[0], tid);
    __syncthreads();

    f32x4 cs[8] = {}, cr[8] = {};
    stage_load(sr, WT1, 256, 64, tid);
    #pragma unroll
    for (int ks = 0; ks < 2; ++ks)
        #pragma unroll
        for (int f = 0; f < 8; ++f)
            cs[f] = MFMA(a[ks], ldsB(Bs[0], f * 16 + l15, ks * 32 + l4 * 8), cs[f]);
    stage_write(sr, Bs[1], tid);
    __syncthreads();
    stage_load(sr, WT1, 256, 128, tid);
    #pragma unroll
    for (int ks = 0; ks < 2; ++ks)
        #pragma unroll
        for (int f = 0; f < 8; ++f)
            cs[f] = MFMA(a[2 + ks], ldsB(Bs[1], f * 16 + l15, ks * 32 + l4 * 8), cs[f]);
    stage_write(sr, Bs[0], tid);
    __syncthreads();
    stage_load(sr, WT1, 256, 192, tid);
    #pragma unroll
    for (int ks = 0; ks < 2; ++ks)
        #pragma unroll
        for (int f = 0; f < 8; ++f)
            cr[f] = MFMA(a[ks], ldsB(Bs[0], f * 16 + l15, ks * 32 + l4 * 8), cr[f]);
    stage_write(sr, Bs[1], tid);
    __syncthreads();
    #pragma unroll
    for (int ks = 0; ks < 2; ++ks)
        #pragma unroll
        for (int f = 0; f < 8; ++f)
            cr[f] = MFMA(a[2 + ks], ldsB(Bs[1], f * 16 + l15, ks * 32 + l4 * 8), cr[f]);

    #pragma unroll
    for (int fp = 0; fp < 4; ++fp) {
        float bl = bn1[fp * 32 + l15], bh = bn1[fp * 32 + 16 + l15];
        #pragma unroll
        for (int r = 0; r < 4; ++r) {
            size_t o = (size_t)(n0 + crow + r) * 64 + fp * 16 + l15;
            sprojP[o] = pk2(cs[2 * fp][r] + bl, cs[2 * fp + 1][r] + bh);
            rprojP[o] = pk2(cr[2 * fp][r], cr[2 * fp + 1][r]);
        }
    }
}

// ---------------- per-layer: edge messages ----------------

__global__ __launch_bounds__(256, 2) void edge_mfma_kernel(
    const unsigned* __restrict__ sprojP, const unsigned* __restrict__ rprojP,
    const int* __restrict__ ssend, const int* __restrict__ srecv,
    const float* __restrict__ sdv, const float* __restrict__ scv,
    const unsigned short* __restrict__ WT2, const float* __restrict__ bn2,
    const unsigned short* __restrict__ WTe1, const float* __restrict__ be1,
    const unsigned short* __restrict__ WTe2, const float* __restrict__ be2,
    unsigned* __restrict__ mbufu)
{
    __shared__ unsigned short h1[128 * 128];   // 32 KB act tile (swizzled 256B rows)
    __shared__ unsigned short Bs[2][64 * 128]; // 2 x 16 KB B panels
    const int tid = threadIdx.x;
    const int e0 = blockIdx.x * 128;
    const int wv = tid >> 6, l = tid & 63, l15 = l & 15, l4 = l >> 4;
    const int er0 = wv * 32 + l15, er1 = er0 + 16;
    const int crow = wv * 32 + l4 * 4;

    StageReg sr;
    // ---- P0: prefetch WT2 k0 -> Bs[0]; h1 = ssp(sproj[s] + rproj[r])
    stage_load(sr, WT2, 128, 0, tid);
    #pragma unroll 4
    for (int it = 0; it < 32; ++it) {
        int e = wv * 32 + it;
        int sn = ssend[e0 + e], rn = srecv[e0 + e];
        unsigned sp = sprojP[(size_t)sn * 64 + l];
        unsigned rp = rprojP[(size_t)rn * 64 + l];
        actW(h1, e, l, pk2(sspf(bflo(sp) + bflo(rp)), sspf(bfhi(sp) + bfhi(rp))));
    }
    stage_write(sr, Bs[0], tid);
    __syncthreads();

    // ---- P1: prefetch WT2 k64 -> Bs[1]; GEMM2 chunk0
    f32x4 m0[8] = {}, m1[8] = {};
    stage_load(sr, WT2, 128, 64, tid);
    #pragma unroll
    for (int ks = 0; ks < 2; ++ks) {
        short8 a0 = ldsA(h1, er0, ks * 32 + l4 * 8);
        short8 a1 = ldsA(h1, er1, ks * 32 + l4 * 8);
        #pragma unroll
        for (int f = 0; f < 8; ++f) {
            short8 b = ldsB(Bs[0], f * 16 + l15, ks * 32 + l4 * 8);
            m0[f] = MFMA(a0, b, m0[f]);
            m1[f] = MFMA(a1, b, m1[f]);
        }
    }
    stage_write(sr, Bs[1], tid);
    __syncthreads();

    // ---- P2: prefetch WTe1 -> Bs[0]; GEMM2 chunk1
    stage_load(sr, WTe1, 64, 0, tid);
    #pragma unroll
    for (int ks = 0; ks < 2; ++ks) {
        short8 a0 = ldsA(h1, er0, 64 + ks * 32 + l4 * 8);
        short8 a1 = ldsA(h1, er1, 64 + ks * 32 + l4 * 8);
        #pragma unroll
        for (int f = 0; f < 8; ++f) {
            short8 b = ldsB(Bs[1], f * 16 + l15, ks * 32 + l4 * 8);
            m0[f] = MFMA(a0, b, m0[f]);
            m1[f] = MFMA(a1, b, m1[f]);
        }
    }
    stage_write(sr, Bs[0], tid);
    __syncthreads();

    // pack m_node + bn2 -> bf16 pairs
    unsigned mnp0[16], mnp1[16];
    #pragma unroll
    for (int fp = 0; fp < 4; ++fp) {
        float bl = bn2[fp * 32 + l15], bh = bn2[fp * 32 + 16 + l15];
        #pragma unroll
        for (int r = 0; r < 4; ++r) {
            mnp0[fp * 4 + r] = pk2(m0[2 * fp][r] + bl, m0[2 * fp + 1][r] + bh);
            mnp1[fp * 4 + r] = pk2(m1[2 * fp][r] + bl, m1[2 * fp + 1][r] + bh);
        }
    }

    // ---- P3: prefetch WTe2 k0 -> Bs[1]; GEMM3 rbf @ We1 (A in regs, HW exp2, paired pack)
    f32x4 c0[8] = {}, c1[8] = {};
    stage_load(sr, WTe2, 128, 0, tid);
    {
        const float cg = -72.134752044448170f;   // -50*log2(e)
        float dv0 = sdv[e0 + er0], dv1 = sdv[e0 + er1];
        #pragma unroll
        for (int ks = 0; ks < 2; ++ks) {
            union { short8 s; unsigned u[4]; } A0, A1;
            #pragma unroll
            for (int jp = 0; jp < 4; ++jp) {
                int k = ks * 32 + l4 * 8 + jp * 2;
                float t0 = dv0 - 0.1f * (float)k, t1 = dv0 - 0.1f * (float)(k + 1);
                float u0 = dv1 - 0.1f * (float)k, u1 = dv1 - 0.1f * (float)(k + 1);
                float e00 = (k     < 50) ? EXP2H(cg * t0 * t0) : 0.0f;
                float e01 = (k + 1 < 50) ? EXP2H(cg * t1 * t1) : 0.0f;
                float e10 = (k     < 50) ? EXP2H(cg * u0 * u0) : 0.0f;
                float e11 = (k + 1 < 50) ? EXP2H(cg * u1 * u1) : 0.0f;
                A0.u[jp] = pk2(e00, e01);
                A1.u[jp] = pk2(e10, e11);
            }
            #pragma unroll
            for (int f = 0; f < 8; ++f) {
                short8 b = ldsB(Bs[0], f * 16 + l15, ks * 32 + l4 * 8);
                c0[f] = MFMA(A0.s, b, c0[f]);
                c1[f] = MFMA(A1.s, b, c1[f]);
            }
        }
    }
    stage_write(sr, Bs[1], tid);
    __syncthreads();

    // ---- P4: prefetch WTe2 k64 -> Bs[0]; filt = ssp(. + be1) -> h1
    stage_load(sr, WTe2, 128, 64, tid);
    #pragma unroll
    for (int fp = 0; fp < 4; ++fp) {
        float bl = be1[fp * 32 + l15], bh = be1[fp * 32 + 16 + l15];
        #pragma unroll
        for (int r = 0; r < 4; ++r) {
            actW(h1, crow + r, fp * 16 + l15,
                 pk2(sspf(c0[2 * fp][r] + bl), sspf(c0[2 * fp + 1][r] + bh)));
            actW(h1, crow + r + 16, fp * 16 + l15,
                 pk2(sspf(c1[2 * fp][r] + bl), sspf(c1[2 * fp + 1][r] + bh)));
        }
    }
    stage_write(sr, Bs[0], tid);
    __syncthreads();

    // ---- P5: GEMM4 both chunks (Bs[1]=k0, Bs[0]=k64); combine; store
    f32x4 g0[8] = {}, g1[8] = {};
    #pragma unroll
    for (int ks = 0; ks < 2; ++ks) {
        short8 a0 = ldsA(h1, er0, ks * 32 + l4 * 8);
        short8 a1 = ldsA(h1, er1, ks * 32 + l4 * 8);
        #pragma unroll
        for (int f = 0; f < 8; ++f) {
            short8 b = ldsB(Bs[1], f * 16 + l15, ks * 32 + l4 * 8);
            g0[f] = MFMA(a0, b, g0[f]);
            g1[f] = MFMA(a1, b, g1[f]);
        }
    }
    #pragma unroll
    for (int ks = 0; ks < 2; ++ks) {
        short8 a0 = ldsA(h1, er0, 64 + ks * 32 + l4 * 8);
        short8 a1 = ldsA(h1, er1, 64 + ks * 32 + l4 * 8);
        #pragma unroll
        for (int f = 0; f < 8; ++f) {
            short8 b = ldsB(Bs[0], f * 16 + l15, ks * 32 + l4 * 8);
            g0[f] = MFMA(a0, b, g0[f]);
            g1[f] = MFMA(a1, b, g1[f]);
        }
    }

    #pragma unroll
    for (int r = 0; r < 4; ++r) {
        float cu0 = scv[e0 + crow + r], cu1 = scv[e0 + crow + 16 + r];
        #pragma unroll
        for (int fp = 0; fp < 4; ++fp) {
            float bl = be2[fp * 32 + l15], bh = be2[fp * 32 + 16 + l15];
            unsigned v0 = mnp0[fp * 4 + r], v1 = mnp1[fp * 4 + r];
            unsigned o0 = pk2(bflo(v0) * ((g0[2 * fp][r] + bl) * cu0),
                              bfhi(v0) * ((g0[2 * fp + 1][r] + bh) * cu0));
            unsigned o1 = pk2(bflo(v1) * ((g1[2 * fp][r] + bl) * cu1),
                              bfhi(v1) * ((g1[2 * fp + 1][r] + bh) * cu1));
            mbufu[(size_t)(e0 + crow + r) * 64 + fp * 16 + l15] = o0;
            mbufu[(size_t)(e0 + crow + 16 + r) * 64 + fp * 16 + l15] = o1;
        }
    }
}

// ---------------- per-layer: parallel segment-sum (1 wave per node row) ----------------

__global__ __launch_bounds__(256, 8) void segsum_kernel(
    const unsigned* __restrict__ mbufu, const int* __restrict__ segs,
    unsigned* __restrict__ msumP)
{
    const int wv = threadIdx.x >> 6, u = threadIdx.x & 63;
    const int row = blockIdx.x * 4 + wv;
    const int s0 = segs[row], s1 = segs[row + 1];
    float aL0 = 0, aH0 = 0, aL1 = 0, aH1 = 0, aL2 = 0, aH2 = 0, aL3 = 0, aH3 = 0;
    int s = s0;
    for (; s + 4 <= s1; s += 4) {
        unsigned v0 = mbufu[(size_t)(s + 0) * 64 + u];
        unsigned v1 = mbufu[(size_t)(s + 1) * 64 + u];
        unsigned v2 = mbufu[(size_t)(s + 2) * 64 + u];
        unsigned v3 = mbufu[(size_t)(s + 3) * 64 + u];
        aL0 += bflo(v0); aH0 += bfhi(v0);
        aL1 += bflo(v1); aH1 += bfhi(v1);
        aL2 += bflo(v2); aH2 += bfhi(v2);
        aL3 += bflo(v3); aH3 += bfhi(v3);
    }
    for (; s < s1; ++s) {
        unsigned v = mbufu[(size_t)s * 64 + u];
        aL0 += bflo(v); aH0 += bfhi(v);
    }
    msumP[(size_t)row * 64 + u] = pk2((aL0 + aL1) + (aL2 + aL3), (aH0 + aH1) + (aH2 + aH3));
}

// ---------------- per-layer: state MLP ----------------

__global__ __launch_bounds__(256, 3) void node_mfma_kernel(
    const unsigned* __restrict__ msumP,
    const unsigned short* __restrict__ WTs1, const float* __restrict__ bs1,
    const unsigned short* __restrict__ WTs2, const float* __restrict__ bs2,
    float* __restrict__ node_state, unsigned short* __restrict__ nsb,
    float* __restrict__ out_l)
{
    __shared__ unsigned short ah[64 * 128];
    __shared__ unsigned short Bs[128 * 64];
    int tid = threadIdx.x;
    int n0 = blockIdx.x * 64;
    #pragma unroll
    for (int it = 0; it < 16; ++it) {
        int idx = it * 256 + tid;                 // 64 rows x 64 dwords
        int i = idx >> 6, u = idx & 63;
        unsigned v = msumP[(size_t)(n0 + i) * 64 + u];
        *(unsigned*)((char*)ah + i * 256 + ((u * 4) ^ ((i & 7) << 4))) = v;
    }
    __syncthreads();
    const int wave = tid >> 6, l = tid & 63, l15 = l & 15, l4 = l >> 4;
    const int er = wave * 16 + l15, crow = wave * 16 + l4 * 4;

    f32x4 c1[8] = {};
    #pragma unroll
    for (int c = 0; c < 2; ++c) {
        stage_b64(WTs1, 128, c * 64, Bs, tid);
        __syncthreads();
        #pragma unroll
        for (int ks = 0; ks < 2; ++ks) {
            short8 a = ldsA(ah, er, c * 64 + ks * 32 + l4 * 8);
            #pragma unroll
            for (int f = 0; f < 8; ++f) {
                short8 b = ldsB(Bs, f * 16 + l15, ks * 32 + l4 * 8);
                c1[f] = MFMA(a, b, c1[f]);
            }
        }
        __syncthreads();
    }
    #pragma unroll
    for (int fp = 0; fp < 4; ++fp) {
        float bl = bs1[fp * 32 + l15], bh = bs1[fp * 32 + 16 + l15];
        #pragma unroll
        for (int r = 0; r < 4; ++r)
            actW(ah, crow + r, fp * 16 + l15,
                 pk2(sspf(c1[2 * fp][r] + bl), sspf(c1[2 * fp + 1][r] + bh)));
    }
    __syncthreads();

    f32x4 c2[8] = {};
    #pragma unroll
    for (int c = 0; c < 2; ++c) {
        stage_b64(WTs2, 128, c * 64, Bs, tid);
        __syncthreads();
        #pragma unroll
        for (int ks = 0; ks < 2; ++ks) {
            short8 a = ldsA(ah, er, c * 64 + ks * 32 + l4 * 8);
            #pragma unroll
            for (int f = 0; f < 8; ++f) {
                short8 b = ldsB(Bs, f * 16 + l15, ks * 32 + l4 * 8);
                c2[f] = MFMA(a, b, c2[f]);
            }
        }
        __syncthreads();
    }

    #pragma unroll
    for (int r = 0; r < 4; ++r) {
        int row = n0 + crow + r;
        float vv[8];
        #pragma unroll
        for (int f = 0; f < 8; ++f) {
            int n = f * 16 + l15;
            float v = node_state[(size_t)row * 128 + n] + c2[f][r] + bs2[n];
            node_state[(size_t)row * 128 + n] = v;
            out_l[(size_t)row * 128 + n] = v;
            vv[f] = v;
        }
        #pragma unroll
        for (int fp = 0; fp < 4; ++fp)
            *(unsigned*)&nsb[(size_t)row * 128 + (fp * 16 + l15) * 2] = pk2(vv[2 * fp], vv[2 * fp + 1]);
    }
}

// ---------------- host ----------------

extern "C" void kernel_launch(void* const* d_in, const int* in_sizes, int n_in,
                              void* d_out, int out_size, void* d_ws, size_t ws_size,
                              hipStream_t stream)
{
    const int*   nodes = (const int*)d_in[0];
    const int*   ae    = (const int*)d_in[1];
    const float* aef   = (const float*)d_in[2];
    const float* emb   = (const float*)d_in[5];
    const float* Wn1 = (const float*)d_in[6];  const float* bn1 = (const float*)d_in[7];
    const float* Wn2 = (const float*)d_in[8];  const float* bn2 = (const float*)d_in[9];
    const float* We1 = (const float*)d_in[10]; const float* be1 = (const float*)d_in[11];
    const float* We2 = (const float*)d_in[12]; const float* be2 = (const float*)d_in[13];
    const float* Ws1 = (const float*)d_in[14]; const float* bs1 = (const float*)d_in[15];
    const float* Ws2 = (const float*)d_in[16]; const float* bs2 = (const float*)d_in[17];
    float* out = (float*)d_out;

    char* ws = (char*)d_ws;
    const size_t MB = 1u << 20;
    float*          node_state = (float*)(ws);                    // 8 MB
    unsigned short* nsb        = (unsigned short*)(ws + 8 * MB);  // 4 MB
    unsigned*       mbufu      = (unsigned*)(ws + 12 * MB);       // 64 MB
    int*   ssend  = (int*)(ws + 76 * MB);
    int*   srecv  = (int*)(ws + 77 * MB);
    float* sdv    = (float*)(ws + 78 * MB);
    float* scv    = (float*)(ws + 79 * MB);
    int*   cnt    = (int*)(ws + 80 * MB);
    int*   segs   = (int*)(ws + 80 * MB + 256 * 1024);
    int*   cursor = (int*)(ws + 80 * MB + 512 * 1024);
    unsigned short* WT1  = (unsigned short*)(ws + 81 * MB);
    unsigned short* WT2  = (unsigned short*)(ws + 81 * MB + 256 * 1024);
    unsigned short* WTe1 = (unsigned short*)(ws + 81 * MB + 512 * 1024);
    unsigned short* WTe2 = (unsigned short*)(ws + 81 * MB + 768 * 1024);
    unsigned short* WTs1 = (unsigned short*)(ws + 82 * MB);
    unsigned short* WTs2 = (unsigned short*)(ws + 82 * MB + 256 * 1024);
    unsigned* sprojP = (unsigned*)(ws + 83 * MB);                 // 4 MB
    unsigned* rprojP = (unsigned*)(ws + 87 * MB);                 // 4 MB
    unsigned* msumP  = (unsigned*)(ws + 91 * MB);                 // 4 MB

    wprep_kernel<<<(LNUM * 128 * 256 + 255) / 256, 256, 0, stream>>>(Wn1, WT1, 256, 256, 1);
    wprep_kernel<<<(LNUM * 128 * 128 + 255) / 256, 256, 0, stream>>>(Wn2, WT2, 128, 128, 1);
    wprep_kernel<<<(LNUM * 128 * 64  + 255) / 256, 256, 0, stream>>>(We1, WTe1, 50, 64, 0);
    wprep_kernel<<<(LNUM * 128 * 128 + 255) / 256, 256, 0, stream>>>(We2, WTe2, 128, 128, 1);
    wprep_kernel<<<(LNUM * 128 * 128 + 255) / 256, 256, 0, stream>>>(Ws1, WTs1, 128, 128, 1);
    wprep_kernel<<<(LNUM * 128 * 128 + 255) / 256, 256, 0, stream>>>(Ws2, WTs2, 128, 128, 1);
    init_nodes_kernel<<<NTOT * 128 / 256, 256, 0, stream>>>(nodes, emb, node_state, nsb);
    hipMemsetAsync(cnt, 0, NTOT * sizeof(int), stream);
    count_kernel<<<ETOT / 256, 256, 0, stream>>>(ae, cnt);
    scan_kernel<<<1, 256, 0, stream>>>(cnt, segs, cursor);
    scatter_kernel<<<ETOT / 256, 256, 0, stream>>>(ae, aef, cursor, ssend, srecv, sdv, scv);

    for (int l = 0; l < LNUM; ++l) {
        nodeproj_kernel<<<NTOT / 64, 256, 0, stream>>>(
            nsb, WT1 + (size_t)l * 128 * 256, bn1 + (size_t)l * 128, sprojP, rprojP);
        edge_mfma_kernel<<<ETOT / 128, 256, 0, stream>>>(
            sprojP, rprojP, ssend, srecv, sdv, scv,
            WT2 + (size_t)l * 128 * 128, bn2 + (size_t)l * 128,
            WTe1 + (size_t)l * 128 * 64, be1 + (size_t)l * 128,
            WTe2 + (size_t)l * 128 * 128, be2 + (size_t)l * 128,
            mbufu);
        segsum_kernel<<<NTOT / 4, 256, 0, stream>>>(mbufu, segs, msumP);
        node_mfma_kernel<<<NTOT / 64, 256, 0, stream>>>(
            msumP,
            WTs1 + (size_t)l * 128 * 128, bs1 + (size_t)l * 128,
            WTs2 + (size_t)l * 128 * 128, bs2 + (size_t)l * 128,
            node_state, nsb, out + (size_t)l * NTOT * 128);
    }
}

// Round 8
// 345.175 us; speedup vs baseline: 8.9150x; 1.0285x over previous
//
#include <hip/hip_runtime.h>
#include <hip/hip_bf16.h>
#include <math.h>

#define BQ 8
#define NPER 2048
#define EPER 32768
#define NTOT (BQ * NPER)          // 16384
#define ETOT (BQ * EPER)          // 262144
#define HDIM 128
#define LNUM 3
#define GTN 2048                  // gate table entries over d in [0,5)

typedef __attribute__((ext_vector_type(8))) short short8;
typedef __attribute__((ext_vector_type(4))) float f32x4;

__device__ __forceinline__ short f2bf(float x) {
    union { float f; unsigned u; } v; v.f = x;
    unsigned r = v.u + 0x7fffu + ((v.u >> 16) & 1u);
    return (short)(r >> 16);
}
__device__ __forceinline__ unsigned pk2(float lo, float hi) {
    union { __hip_bfloat162 h; unsigned u; } v;
    float2 f; f.x = lo; f.y = hi;
    v.h = __float22bfloat162_rn(f);
    return v.u;
}
__device__ __forceinline__ float bflo(unsigned v) {
    union { unsigned u; float f; } x; x.u = v << 16; return x.f;
}
__device__ __forceinline__ float bfhi(unsigned v) {
    union { unsigned u; float f; } x; x.u = v & 0xffff0000u; return x.f;
}
// softplus(x)-ln2 via HW transcendentals (v_exp_f32 / v_log_f32)
__device__ __forceinline__ float sspf(float x) {
    float e = __builtin_amdgcn_exp2f(x * 1.4426950408889634f);
    return 0.6931471805599453f * (__builtin_amdgcn_logf(1.0f + e) - 1.0f);
}
#define EXP2H(x) __builtin_amdgcn_exp2f(x)

// ---- LDS helpers (XOR-swizzled; act rows 256B, B rows 128B) ----
__device__ __forceinline__ short8 ldsA(const unsigned short* t, int row, int pos) {
    return *(const short8*)((const char*)t + row * 256 + ((pos * 2) ^ ((row & 7) << 4)));
}
__device__ __forceinline__ short8 ldsB(const unsigned short* t, int n, int pos) {
    return *(const short8*)((const char*)t + n * 128 + ((pos * 2) ^ ((n & 7) << 4)));
}
__device__ __forceinline__ void actW(unsigned short* t, int row, int dw, unsigned v) {
    *(unsigned*)((char*)t + row * 256 + ((dw * 4) ^ ((row & 7) << 4))) = v;
}

// ---- T14 async-STAGE split ----
struct StageReg { uint4 v[4]; };
__device__ __forceinline__ void stage_load(StageReg& s, const unsigned short* __restrict__ src,
                                           int strideK, int kbase, int tid) {
    #pragma unroll
    for (int it = 0; it < 4; ++it) {
        int u = it * 256 + tid;
        int n = u >> 3, kd8 = u & 7;     // LINEAR source
        s.v[it] = *(const uint4*)&src[(size_t)n * strideK + kbase + kd8 * 8];
    }
}
__device__ __forceinline__ void stage_write(const StageReg& s, unsigned short* Bs, int tid) {
    #pragma unroll
    for (int it = 0; it < 4; ++it) {
        int u = it * 256 + tid;
        int n = u >> 3;
        *(uint4*)((char*)Bs + ((u * 16) ^ ((n & 7) << 4))) = s.v[it];
    }
}
// legacy 8B-unit stager (node kernel)
__device__ __forceinline__ void stage_b64(const unsigned short* __restrict__ src, int strideK, int kbase,
                                          unsigned short* __restrict__ Bs, int tid) {
    #pragma unroll
    for (int it = 0; it < 8; ++it) {
        int i = it * 256 + tid;
        int n = i >> 4, kd2 = i & 15;
        uint2 v = *(const uint2*)&src[(size_t)n * strideK + kbase + kd2 * 4];
        *(uint2*)((char*)Bs + n * 128 + ((kd2 * 8) ^ ((n & 7) << 4))) = v;
    }
}

#define MFMA(A, B, C) __builtin_amdgcn_mfma_f32_16x16x32_bf16(A, B, C, 0, 0, 0)

// ---------------- once-per-launch prep ----------------

__global__ __launch_bounds__(256) void wprep_kernel(
    const float* __restrict__ W, unsigned short* __restrict__ WT,
    int K, int KP, int doperm)
{
    int idx = blockIdx.x * 256 + threadIdx.x;
    int total = LNUM * 128 * KP;
    if (idx >= total) return;
    int l = idx / (128 * KP);
    int rem = idx - l * (128 * KP);
    int n = rem / KP;
    int p = rem - n * KP;
    int k;
    if (doperm) {
        int half = p >> 7, pp = p & 127;
        k = (half << 7) | ((pp >> 5) << 5) | ((pp & 1) << 4) | ((pp & 31) >> 1);
    } else k = p;
    float v = (k < K) ? W[((size_t)l * K + k) * 128 + n] : 0.0f;
    WT[idx] = (unsigned short)f2bf(v);
}

// gate table: gtab[l][idx][feat->permuted dword slot] = gate(d)*cut(d), d = idx*5/GTN
__global__ __launch_bounds__(128) void gtab_kernel(
    const float* __restrict__ We1, const float* __restrict__ be1,
    const float* __restrict__ We2, const float* __restrict__ be2,
    float* __restrict__ gtab)
{
    const int idx = blockIdx.x, l = blockIdx.y, t = threadIdx.x;
    const float d = (float)idx * (5.0f / (float)GTN);
    __shared__ float rbf[64];
    __shared__ float hid[128];
    if (t < 64) {
        float tt = d - 0.1f * (float)t;
        rbf[t] = (t < 50) ? EXP2H(-72.134752044448170f * tt * tt) : 0.0f;
    }
    __syncthreads();
    float acc = be1[l * 128 + t];
    for (int k = 0; k < 50; ++k)
        acc = fmaf(rbf[k], We1[((size_t)l * 50 + k) * 128 + t], acc);
    hid[t] = sspf(acc);
    __syncthreads();
    float g = be2[l * 128 + t];
    for (int k = 0; k < 128; ++k)
        g = fmaf(hid[k], We2[((size_t)l * 128 + k) * 128 + t], g);
    float cut = 1.0f / (1.0f + EXP2H(7.2134752044448170f * (d - 3.5f)));
    // feature t lives in dword j = (t>>5)*16 + (t&15), slot hi = (t>>4)&1
    int j = ((t >> 5) << 4) | (t & 15);
    int hi = (t >> 4) & 1;
    gtab[((size_t)(l * GTN + idx)) * 128 + j * 2 + hi] = g * cut;
}

__global__ __launch_bounds__(256) void init_nodes_kernel(
    const int* __restrict__ nodes, const float* __restrict__ emb,
    float* __restrict__ node_state, unsigned short* __restrict__ nsb)
{
    int idx = blockIdx.x * 256 + threadIdx.x;
    int n = idx >> 7, p = idx & 127;
    int j = ((p >> 5) << 5) | ((p & 1) << 4) | ((p & 31) >> 1);
    float v = emb[(size_t)nodes[n] * 128 + j];
    nsb[idx] = (unsigned short)f2bf(v);
    node_state[(n << 7) + j] = v;
}

__global__ __launch_bounds__(256) void count_kernel(const int* __restrict__ ae, int* __restrict__ cnt)
{
    int g = blockIdx.x * 256 + threadIdx.x;
    int b = g >> 15;
    atomicAdd(&cnt[ae[2 * g + 1] + b * NPER], 1);
}

__global__ __launch_bounds__(256) void scan_kernel(
    const int* __restrict__ cnt, int* __restrict__ segs, int* __restrict__ cursor)
{
    __shared__ int part[256];
    int t = threadIdx.x;
    int base = t * 64;
    int s = 0;
    for (int i = 0; i < 64; ++i) s += cnt[base + i];
    part[t] = s;
    __syncthreads();
    for (int ofs = 1; ofs < 256; ofs <<= 1) {
        int v = part[t];
        int add = (t >= ofs) ? part[t - ofs] : 0;
        __syncthreads();
        part[t] = v + add;
        __syncthreads();
    }
    int run = part[t] - s;
    for (int i = 0; i < 64; ++i) {
        segs[base + i] = run;
        cursor[base + i] = run;
        run += cnt[base + i];
    }
    if (t == 255) segs[NTOT] = run;
}

__global__ __launch_bounds__(256) void scatter_kernel(
    const int* __restrict__ ae, const float* __restrict__ aef, int* __restrict__ cursor,
    int* __restrict__ ssend, int* __restrict__ srecv, float* __restrict__ sdv)
{
    int g = blockIdx.x * 256 + threadIdx.x;
    int b = g >> 15;
    int sn = ae[2 * g] + b * NPER, rv = ae[2 * g + 1] + b * NPER;
    int pos = atomicAdd(&cursor[rv], 1);
    ssend[pos] = sn; srecv[pos] = rv;
    sdv[pos] = aef[g];
}

// ---------------- per-layer: node projections ----------------

__global__ __launch_bounds__(256, 3) void nodeproj_kernel(
    const unsigned short* __restrict__ nsb,
    const unsigned short* __restrict__ WT1, const float* __restrict__ bn1,
    unsigned* __restrict__ sprojP, unsigned* __restrict__ rprojP)
{
    __shared__ unsigned short Bs[2][64 * 128];
    const int tid = threadIdx.x;
    const int n0 = blockIdx.x * 64;
    const int wv = tid >> 6, l = tid & 63, l15 = l & 15, l4 = l >> 4;
    const int er = wv * 16 + l15, crow = wv * 16 + l4 * 4;

    short8 a[4];
    #pragma unroll
    for (int ks = 0; ks < 4; ++ks)
        a[ks] = *(const short8*)&nsb[(size_t)(n0 + er) * 128 + ks * 32 + l4 * 8];

    StageReg sr;
    stage_load(sr, WT1, 256, 0, tid);
    stage_write(sr, Bs[0], tid);
    __syncthreads();

    f32x4 cs[8] = {}, cr[8] = {};
    stage_load(sr, WT1, 256, 64, tid);
    #pragma unroll
    for (int ks = 0; ks < 2; ++ks)
        #pragma unroll
        for (int f = 0; f < 8; ++f)
            cs[f] = MFMA(a[ks], ldsB(Bs[0], f * 16 + l15, ks * 32 + l4 * 8), cs[f]);
    stage_write(sr, Bs[1], tid);
    __syncthreads();
    stage_load(sr, WT1, 256, 128, tid);
    #pragma unroll
    for (int ks = 0; ks < 2; ++ks)
        #pragma unroll
        for (int f = 0; f < 8; ++f)
            cs[f] = MFMA(a[2 + ks], ldsB(Bs[1], f * 16 + l15, ks * 32 + l4 * 8), cs[f]);
    stage_write(sr, Bs[0], tid);
    __syncthreads();
    stage_load(sr, WT1, 256, 192, tid);
    #pragma unroll
    for (int ks = 0; ks < 2; ++ks)
        #pragma unroll
        for (int f = 0; f < 8; ++f)
            cr[f] = MFMA(a[ks], ldsB(Bs[0], f * 16 + l15, ks * 32 + l4 * 8), cr[f]);
    stage_write(sr, Bs[1], tid);
    __syncthreads();
    #pragma unroll
    for (int ks = 0; ks < 2; ++ks)
        #pragma unroll
        for (int f = 0; f < 8; ++f)
            cr[f] = MFMA(a[2 + ks], ldsB(Bs[1], f * 16 + l15, ks * 32 + l4 * 8), cr[f]);

    #pragma unroll
    for (int fp = 0; fp < 4; ++fp) {
        float bl = bn1[fp * 32 + l15], bh = bn1[fp * 32 + 16 + l15];
        #pragma unroll
        for (int r = 0; r < 4; ++r) {
            size_t o = (size_t)(n0 + crow + r) * 64 + fp * 16 + l15;
            sprojP[o] = pk2(cs[2 * fp][r] + bl, cs[2 * fp + 1][r] + bh);
            rprojP[o] = pk2(cr[2 * fp][r], cr[2 * fp + 1][r]);
        }
    }
}

// ---------------- per-layer: edge messages (GEMM2 only + gate table) ----------------

__global__ __launch_bounds__(256, 3) void edge_mfma_kernel(
    const unsigned* __restrict__ sprojP, const unsigned* __restrict__ rprojP,
    const int* __restrict__ ssend, const int* __restrict__ srecv,
    const float* __restrict__ sdv,
    const unsigned short* __restrict__ WT2, const float* __restrict__ bn2,
    const float* __restrict__ gtab,
    unsigned* __restrict__ mbufu)
{
    __shared__ unsigned short h1[128 * 128];   // 32 KB act tile
    __shared__ unsigned short Bs[128 * 64];    // 16 KB B panel
    const int tid = threadIdx.x;
    const int e0 = blockIdx.x * 128;
    const int wv = tid >> 6, l = tid & 63, l15 = l & 15, l4 = l >> 4;
    const int er0 = wv * 32 + l15, er1 = er0 + 16;
    const int crow = wv * 32 + l4 * 4;

    StageReg sr;
    // prefetch WT2 chunk0; compute h1 = ssp(sproj[s] + rproj[r])
    stage_load(sr, WT2, 128, 0, tid);
    #pragma unroll 4
    for (int it = 0; it < 32; ++it) {
        int e = wv * 32 + it;
        int sn = ssend[e0 + e], rn = srecv[e0 + e];
        unsigned sp = sprojP[(size_t)sn * 64 + l];
        unsigned rp = rprojP[(size_t)rn * 64 + l];
        actW(h1, e, l, pk2(sspf(bflo(sp) + bflo(rp)), sspf(bfhi(sp) + bfhi(rp))));
    }
    stage_write(sr, Bs, tid);
    __syncthreads();

    // hoist gate-table indices (independent of MFMA)
    int i0a[4], i0b[4];
    float wa[4], wb[4];
    #pragma unroll
    for (int r = 0; r < 4; ++r) {
        float fia = sdv[e0 + crow + r] * ((float)GTN / 5.0f);
        float fib = sdv[e0 + crow + 16 + r] * ((float)GTN / 5.0f);
        int ia = (int)fia; ia = (ia > GTN - 2) ? GTN - 2 : ia;
        int ib = (int)fib; ib = (ib > GTN - 2) ? GTN - 2 : ib;
        i0a[r] = ia; wa[r] = fia - (float)ia;
        i0b[r] = ib; wb[r] = fib - (float)ib;
    }

    // GEMM2 chunk0; prefetch chunk1
    f32x4 m0[8] = {}, m1[8] = {};
    stage_load(sr, WT2, 128, 64, tid);
    #pragma unroll
    for (int ks = 0; ks < 2; ++ks) {
        short8 a0 = ldsA(h1, er0, ks * 32 + l4 * 8);
        short8 a1 = ldsA(h1, er1, ks * 32 + l4 * 8);
        #pragma unroll
        for (int f = 0; f < 8; ++f) {
            short8 b = ldsB(Bs, f * 16 + l15, ks * 32 + l4 * 8);
            m0[f] = MFMA(a0, b, m0[f]);
            m1[f] = MFMA(a1, b, m1[f]);
        }
    }
    __syncthreads();
    stage_write(sr, Bs, tid);
    __syncthreads();
    // GEMM2 chunk1
    #pragma unroll
    for (int ks = 0; ks < 2; ++ks) {
        short8 a0 = ldsA(h1, er0, 64 + ks * 32 + l4 * 8);
        short8 a1 = ldsA(h1, er1, 64 + ks * 32 + l4 * 8);
        #pragma unroll
        for (int f = 0; f < 8; ++f) {
            short8 b = ldsB(Bs, f * 16 + l15, ks * 32 + l4 * 8);
            m0[f] = MFMA(a0, b, m0[f]);
            m1[f] = MFMA(a1, b, m1[f]);
        }
    }

    // combine: msg = (m + bn2) * lerp(gtab)  -> mbuf
    const float2* gt = (const float2*)gtab;
    float blv[4], bhv[4];
    #pragma unroll
    for (int fp = 0; fp < 4; ++fp) {
        blv[fp] = bn2[fp * 32 + l15];
        bhv[fp] = bn2[fp * 32 + 16 + l15];
    }
    #pragma unroll
    for (int r = 0; r < 4; ++r) {
        #pragma unroll
        for (int fp = 0; fp < 4; ++fp) {
            float2 g0 = gt[(size_t)i0a[r] * 64 + fp * 16 + l15];
            float2 g1 = gt[(size_t)(i0a[r] + 1) * 64 + fp * 16 + l15];
            float gl = fmaf(wa[r], g1.x - g0.x, g0.x);
            float gh = fmaf(wa[r], g1.y - g0.y, g0.y);
            mbufu[(size_t)(e0 + crow + r) * 64 + fp * 16 + l15] =
                pk2((m0[2 * fp][r] + blv[fp]) * gl, (m0[2 * fp + 1][r] + bhv[fp]) * gh);
        }
        #pragma unroll
        for (int fp = 0; fp < 4; ++fp) {
            float2 g0 = gt[(size_t)i0b[r] * 64 + fp * 16 + l15];
            float2 g1 = gt[(size_t)(i0b[r] + 1) * 64 + fp * 16 + l15];
            float gl = fmaf(wb[r], g1.x - g0.x, g0.x);
            float gh = fmaf(wb[r], g1.y - g0.y, g0.y);
            mbufu[(size_t)(e0 + crow + 16 + r) * 64 + fp * 16 + l15] =
                pk2((m1[2 * fp][r] + blv[fp]) * gl, (m1[2 * fp + 1][r] + bhv[fp]) * gh);
        }
    }
}

// ---------------- per-layer: parallel segment-sum ----------------

__global__ __launch_bounds__(256, 8) void segsum_kernel(
    const unsigned* __restrict__ mbufu, const int* __restrict__ segs,
    unsigned* __restrict__ msumP)
{
    const int wv = threadIdx.x >> 6, u = threadIdx.x & 63;
    const int row = blockIdx.x * 4 + wv;
    const int s0 = segs[row], s1 = segs[row + 1];
    float aL0 = 0, aH0 = 0, aL1 = 0, aH1 = 0, aL2 = 0, aH2 = 0, aL3 = 0, aH3 = 0;
    int s = s0;
    for (; s + 4 <= s1; s += 4) {
        unsigned v0 = mbufu[(size_t)(s + 0) * 64 + u];
        unsigned v1 = mbufu[(size_t)(s + 1) * 64 + u];
        unsigned v2 = mbufu[(size_t)(s + 2) * 64 + u];
        unsigned v3 = mbufu[(size_t)(s + 3) * 64 + u];
        aL0 += bflo(v0); aH0 += bfhi(v0);
        aL1 += bflo(v1); aH1 += bfhi(v1);
        aL2 += bflo(v2); aH2 += bfhi(v2);
        aL3 += bflo(v3); aH3 += bfhi(v3);
    }
    for (; s < s1; ++s) {
        unsigned v = mbufu[(size_t)s * 64 + u];
        aL0 += bflo(v); aH0 += bfhi(v);
    }
    msumP[(size_t)row * 64 + u] = pk2((aL0 + aL1) + (aL2 + aL3), (aH0 + aH1) + (aH2 + aH3));
}

// ---------------- per-layer: state MLP ----------------

__global__ __launch_bounds__(256, 3) void node_mfma_kernel(
    const unsigned* __restrict__ msumP,
    const unsigned short* __restrict__ WTs1, const float* __restrict__ bs1,
    const unsigned short* __restrict__ WTs2, const float* __restrict__ bs2,
    float* __restrict__ node_state, unsigned short* __restrict__ nsb,
    float* __restrict__ out_l)
{
    __shared__ unsigned short ah[64 * 128];
    __shared__ unsigned short Bs[128 * 64];
    int tid = threadIdx.x;
    int n0 = blockIdx.x * 64;
    #pragma unroll
    for (int it = 0; it < 16; ++it) {
        int idx = it * 256 + tid;
        int i = idx >> 6, u = idx & 63;
        unsigned v = msumP[(size_t)(n0 + i) * 64 + u];
        *(unsigned*)((char*)ah + i * 256 + ((u * 4) ^ ((i & 7) << 4))) = v;
    }
    __syncthreads();
    const int wave = tid >> 6, l = tid & 63, l15 = l & 15, l4 = l >> 4;
    const int er = wave * 16 + l15, crow = wave * 16 + l4 * 4;

    f32x4 c1[8] = {};
    #pragma unroll
    for (int c = 0; c < 2; ++c) {
        stage_b64(WTs1, 128, c * 64, Bs, tid);
        __syncthreads();
        #pragma unroll
        for (int ks = 0; ks < 2; ++ks) {
            short8 a = ldsA(ah, er, c * 64 + ks * 32 + l4 * 8);
            #pragma unroll
            for (int f = 0; f < 8; ++f) {
                short8 b = ldsB(Bs, f * 16 + l15, ks * 32 + l4 * 8);
                c1[f] = MFMA(a, b, c1[f]);
            }
        }
        __syncthreads();
    }
    #pragma unroll
    for (int fp = 0; fp < 4; ++fp) {
        float bl = bs1[fp * 32 + l15], bh = bs1[fp * 32 + 16 + l15];
        #pragma unroll
        for (int r = 0; r < 4; ++r)
            actW(ah, crow + r, fp * 16 + l15,
                 pk2(sspf(c1[2 * fp][r] + bl), sspf(c1[2 * fp + 1][r] + bh)));
    }
    __syncthreads();

    f32x4 c2[8] = {};
    #pragma unroll
    for (int c = 0; c < 2; ++c) {
        stage_b64(WTs2, 128, c * 64, Bs, tid);
        __syncthreads();
        #pragma unroll
        for (int ks = 0; ks < 2; ++ks) {
            short8 a = ldsA(ah, er, c * 64 + ks * 32 + l4 * 8);
            #pragma unroll
            for (int f = 0; f < 8; ++f) {
                short8 b = ldsB(Bs, f * 16 + l15, ks * 32 + l4 * 8);
                c2[f] = MFMA(a, b, c2[f]);
            }
        }
        __syncthreads();
    }

    #pragma unroll
    for (int r = 0; r < 4; ++r) {
        int row = n0 + crow + r;
        float vv[8];
        #pragma unroll
        for (int f = 0; f < 8; ++f) {
            int n = f * 16 + l15;
            float v = node_state[(size_t)row * 128 + n] + c2[f][r] + bs2[n];
            node_state[(size_t)row * 128 + n] = v;
            out_l[(size_t)row * 128 + n] = v;
            vv[f] = v;
        }
        #pragma unroll
        for (int fp = 0; fp < 4; ++fp)
            *(unsigned*)&nsb[(size_t)row * 128 + (fp * 16 + l15) * 2] = pk2(vv[2 * fp], vv[2 * fp + 1]);
    }
}

// ---------------- host ----------------

extern "C" void kernel_launch(void* const* d_in, const int* in_sizes, int n_in,
                              void* d_out, int out_size, void* d_ws, size_t ws_size,
                              hipStream_t stream)
{
    const int*   nodes = (const int*)d_in[0];
    const int*   ae    = (const int*)d_in[1];
    const float* aef   = (const float*)d_in[2];
    const float* emb   = (const float*)d_in[5];
    const float* Wn1 = (const float*)d_in[6];  const float* bn1 = (const float*)d_in[7];
    const float* Wn2 = (const float*)d_in[8];  const float* bn2 = (const float*)d_in[9];
    const float* We1 = (const float*)d_in[10]; const float* be1 = (const float*)d_in[11];
    const float* We2 = (const float*)d_in[12]; const float* be2 = (const float*)d_in[13];
    const float* Ws1 = (const float*)d_in[14]; const float* bs1 = (const float*)d_in[15];
    const float* Ws2 = (const float*)d_in[16]; const float* bs2 = (const float*)d_in[17];
    float* out = (float*)d_out;

    char* ws = (char*)d_ws;
    const size_t MB = 1u << 20;
    float*          node_state = (float*)(ws);                    // 8 MB
    unsigned short* nsb        = (unsigned short*)(ws + 8 * MB);  // 4 MB
    unsigned*       mbufu      = (unsigned*)(ws + 12 * MB);       // 64 MB
    int*   ssend  = (int*)(ws + 76 * MB);
    int*   srecv  = (int*)(ws + 77 * MB);
    float* sdv    = (float*)(ws + 78 * MB);
    int*   cnt    = (int*)(ws + 80 * MB);
    int*   segs   = (int*)(ws + 80 * MB + 256 * 1024);
    int*   cursor = (int*)(ws + 80 * MB + 512 * 1024);
    unsigned short* WT1  = (unsigned short*)(ws + 81 * MB);
    unsigned short* WT2  = (unsigned short*)(ws + 81 * MB + 256 * 1024);
    unsigned short* WTs1 = (unsigned short*)(ws + 82 * MB);
    unsigned short* WTs2 = (unsigned short*)(ws + 82 * MB + 256 * 1024);
    unsigned* sprojP = (unsigned*)(ws + 83 * MB);                 // 4 MB
    unsigned* rprojP = (unsigned*)(ws + 87 * MB);                 // 4 MB
    unsigned* msumP  = (unsigned*)(ws + 91 * MB);                 // 4 MB
    float*    gtab   = (float*)(ws + 95 * MB);                    // 3 MB (L*GTN*128 f32)

    wprep_kernel<<<(LNUM * 128 * 256 + 255) / 256, 256, 0, stream>>>(Wn1, WT1, 256, 256, 1);
    wprep_kernel<<<(LNUM * 128 * 128 + 255) / 256, 256, 0, stream>>>(Wn2, WT2, 128, 128, 1);
    wprep_kernel<<<(LNUM * 128 * 128 + 255) / 256, 256, 0, stream>>>(Ws1, WTs1, 128, 128, 1);
    wprep_kernel<<<(LNUM * 128 * 128 + 255) / 256, 256, 0, stream>>>(Ws2, WTs2, 128, 128, 1);
    gtab_kernel<<<dim3(GTN, LNUM), 128, 0, stream>>>(We1, be1, We2, be2, gtab);
    init_nodes_kernel<<<NTOT * 128 / 256, 256, 0, stream>>>(nodes, emb, node_state, nsb);
    hipMemsetAsync(cnt, 0, NTOT * sizeof(int), stream);
    count_kernel<<<ETOT / 256, 256, 0, stream>>>(ae, cnt);
    scan_kernel<<<1, 256, 0, stream>>>(cnt, segs, cursor);
    scatter_kernel<<<ETOT / 256, 256, 0, stream>>>(ae, aef, cursor, ssend, srecv, sdv);

    for (int l = 0; l < LNUM; ++l) {
        nodeproj_kernel<<<NTOT / 64, 256, 0, stream>>>(
            nsb, WT1 + (size_t)l * 128 * 256, bn1 + (size_t)l * 128, sprojP, rprojP);
        edge_mfma_kernel<<<ETOT / 128, 256, 0, stream>>>(
            sprojP, rprojP, ssend, srecv, sdv,
            WT2 + (size_t)l * 128 * 128, bn2 + (size_t)l * 128,
            gtab + (size_t)l * GTN * 128,
            mbufu);
        segsum_kernel<<<NTOT / 4, 256, 0, stream>>>(mbufu, segs, msumP);
        node_mfma_kernel<<<NTOT / 64, 256, 0, stream>>>(
            msumP,
            WTs1 + (size_t)l * 128 * 128, bs1 + (size_t)l * 128,
            WTs2 + (size_t)l * 128 * 128, bs2 + (size_t)l * 128,
            node_state, nsb, out + (size_t)l * NTOT * 128);
    }
}